// Round 3
// baseline (10953.770 us; speedup 1.0000x reference)
//
#include <hip/hip_runtime.h>
#include <hip/hip_bf16.h>
#include <stdint.h>
#include <stddef.h>

// ============================================================================
// PPOAgent fused pipeline for MI355X (gfx950)
//   LSTM(1024 steps, BS=512, IN=128, H=256) with done-resets + 2 MLP heads,
//   ALL fused into the recurrent kernel (no hidden materialization).
// done ~ Bernoulli(1/2) => scan factorizes into ~262K independent short
// segments. Build segments on device, bucket-sort by length (descending),
// batch 64/block, run recurrence as ragged MFMA GEMMs with L2-resident
// fragment-packed weights; apply both MLP heads per produced h in-block.
// R3 fix: group-init now fills the FULL h region [256,768) of each A-tile row
// (R1/R2 filled only [256,512) -> first-iteration GEMM read uninit LDS -> NaN).
// ============================================================================

typedef short bf16x8 __attribute__((ext_vector_type(8)));
typedef float f32x4  __attribute__((ext_vector_type(4)));

#define LOG2E 1.44269504088896340736f

__device__ __forceinline__ float fexp2(float x){ return __builtin_amdgcn_exp2f(x); }
__device__ __forceinline__ float frcpf_(float x){ return __builtin_amdgcn_rcpf(x); }
__device__ __forceinline__ float fsig(float x){ return frcpf_(1.0f + fexp2(-x*LOG2E)); }
__device__ __forceinline__ float ftanh_(float x){ return 1.0f - 2.0f*frcpf_(1.0f + fexp2(x*(2.0f*LOG2E))); }

__device__ __forceinline__ short f2bf(float f){
  unsigned u = __builtin_bit_cast(unsigned, f);
  u += 0x7fffu + ((u>>16)&1u);
  return (short)(u>>16);
}
__device__ __forceinline__ float bf2f(short h){
  unsigned u = ((unsigned)(unsigned short)h)<<16;
  return __builtin_bit_cast(float, u);
}

// ---------------- workspace layout (bytes); total ~5.3 MB ----------------
static constexpr size_t WS_WMAIN  = 0;          // packed [Wih;Whh] frag stream, 384x1024 bf16 = 786432
static constexpr size_t WS_WA1P   = 786432;     // 65536
static constexpr size_t WS_WV1P   = 851968;     // 65536
static constexpr size_t WS_WA2P   = 917504;     // 32768
static constexpr size_t WS_WV2P   = 950272;     // 32768
static constexpr size_t WS_BMAIN  = 983040;     // 1024 f32 gate-interleaved bias
static constexpr size_t WS_META   = 1048576;    // nSegs@+0 ; maskMode@+16 ; hist@+4096 ; curs@+12288
static constexpr size_t WS_SEGS   = 1081344;    // 524288 u32
static constexpr size_t WS_SORTED = 3178496;    // 524288 u32  (end: 5275648)

// ============================================================================
// K0a: pack [W_ih; W_hh] into MFMA B-fragment stream + gate-interleaved bias.
// Packed gate index g' = 4*j + q  (j = h index, q in {i,f,g,o}).
// Chunk = (kt, ch, gq): 32 k x 256 g' bf16, fragment-contiguous:
//   addr(short) = chunkIdx*8192 + ntl*512 + lane*8 ; chunkIdx = kt*4+ch*2+gq
// B-frag layout (16x16x32): lane%16 = col n, k = kt*32 + (lane/16)*8 + j
// ============================================================================
__global__ void k0a_packmain(const float* __restrict__ wih, const float* __restrict__ whh,
                             const float* __restrict__ bih, const float* __restrict__ bhh,
                             short* __restrict__ wp, float* __restrict__ bp)
{
  int tidg = blockIdx.x*512 + threadIdx.x;     // 0..49151
  {
    int lane = tidg & 63;
    int nt   = (tidg>>6) & 15;
    int ci   = tidg>>10;                        // 0..47
    int kt = ci>>2;
    int gp = ((ci>>1)&1)*512 + (ci&1)*256 + nt*16 + (lane&15);   // packed gate g'
    int g  = (gp&3)*256 + (gp>>2);                               // original gate row
    int k0 = kt*32 + (lane>>4)*8;
    bf16x8 ov;
#pragma unroll
    for (int j=0;j<8;++j){
      int k = k0 + j;
      float v = (k < 128) ? wih[(size_t)g*128 + k] : whh[(size_t)g*256 + (k-128)];
      ov[j] = f2bf(v);
    }
    *(bf16x8*)(wp + (size_t)tidg*8) = ov;
  }
  if (tidg < 1024) {
    int gp = tidg;
    int g  = (gp&3)*256 + (gp>>2);
    bp[gp] = bih[g] + bhh[g];
  }
}

// K0b: pack head weights (N x K row-major -> frag stream, N=128)
__global__ void k0b_packheads(const float* __restrict__ wa1, const float* __restrict__ wv1,
                              const float* __restrict__ wa2, const float* __restrict__ wv2,
                              short* __restrict__ wa1p, short* __restrict__ wv1p,
                              short* __restrict__ wa2p, short* __restrict__ wv2p)
{
  int p = blockIdx.x*512 + threadIdx.x;     // 0..12287
  const float* src; short* dst; int K; int pl;
  if (p < 4096)       { src=wa1; dst=wa1p; K=256; pl=p; }
  else if (p < 8192)  { src=wv1; dst=wv1p; K=256; pl=p-4096; }
  else if (p < 10240) { src=wa2; dst=wa2p; K=128; pl=p-8192; }
  else                { src=wv2; dst=wv2p; K=128; pl=p-10240; }
  int lane = pl & 63;
  int f    = pl >> 6;
  int nt   = f & 7;
  int kt   = f >> 3;
  int n  = nt*16 + (lane&15);
  int k0 = kt*32 + (lane>>4)*8;
  bf16x8 ov;
#pragma unroll
  for (int j=0;j<8;++j) ov[j] = f2bf(src[(size_t)n*K + k0 + j]);
  *(bf16x8*)(dst + (size_t)pl*8) = ov;
}

// ============================================================================
// K1: detect invalid_action_mask storage layout. If the array is 1-byte bools,
// bytes at i%4!=0 are ~Bernoulli(1/2) nonzero; if int32, they are all zero.
// Samples 16384 bytes (both layouts are larger). flag=1 -> byte layout.
// ============================================================================
__global__ void k1_maskmode(const unsigned char* __restrict__ mask, uint32_t* __restrict__ flag)
{
  int i = blockIdx.x*256 + threadIdx.x;
  uint32_t v = ((i & 3) != 0) ? (uint32_t)mask[i] : 0u;
  if (v) atomicOr((unsigned int*)flag, 1u);
}

// ============================================================================
// K2a: per batch column b (= blockIdx.x), find segment starts, emit records.
// record u32 = (len-1)<<19 | start<<9 | b
// ============================================================================
__global__ void k2a_segments(const int* __restrict__ done, uint32_t* __restrict__ segs,
                             uint32_t* __restrict__ nSegs)
{
  const int b = blockIdx.x;
  const int tid = threadIdx.x;            // 256 threads, 4 t's each
  __shared__ uint16_t starts[1025];
  __shared__ uint32_t cnts[256];
  __shared__ uint32_t basePos;

  uint32_t my[4]; int myn = 0;
  int t0 = tid*4;
#pragma unroll
  for (int i=0;i<4;++i){
    int t = t0 + i;
    int d = done[(size_t)t*512 + b];
    if (t == 0 || d != 0) my[myn++] = (uint32_t)t;
  }
  cnts[tid] = (uint32_t)myn;
  __syncthreads();
  for (int off=1; off<256; off<<=1){
    uint32_t v = (tid >= off) ? cnts[tid-off] : 0u;
    __syncthreads();
    cnts[tid] += v;
    __syncthreads();
  }
  uint32_t myBase = cnts[tid] - (uint32_t)myn;
  uint32_t ns = cnts[255];
  for (int i=0;i<myn;++i) starts[myBase+i] = (uint16_t)my[i];
  if (tid == 0) {
    starts[ns] = 1024;
    basePos = atomicAdd((unsigned int*)nSegs, ns);
  }
  __syncthreads();
  for (uint32_t i = tid; i < ns; i += 256) {
    uint32_t st = starts[i];
    uint32_t ln = (uint32_t)starts[i+1] - st;
    segs[basePos + i] = ((ln-1u)<<19) | (st<<9) | (uint32_t)b;
  }
}

__global__ void k2b_hist(const uint32_t* __restrict__ segs, const uint32_t* __restrict__ nSegs,
                         uint32_t* __restrict__ hist)
{
  uint32_t i = blockIdx.x*512u + threadIdx.x;
  if (i < *nSegs) {
    uint32_t ln = ((segs[i]>>19)&1023u) + 1u;
    atomicAdd((unsigned int*)&hist[ln], 1u);
  }
}

// bucketStart[len] = #segments with length > len  (descending sort)
__global__ void k2c_scan(const uint32_t* __restrict__ hist, uint32_t* __restrict__ curs)
{
  __shared__ uint32_t s[1024];
  const int tid = threadIdx.x;            // len = tid+1
  uint32_t own = hist[tid+1];
  s[tid] = own;
  __syncthreads();
  for (int off=1; off<1024; off<<=1){
    uint32_t v = (tid+off < 1024) ? s[tid+off] : 0u;
    __syncthreads();
    s[tid] += v;
    __syncthreads();
  }
  curs[tid+1] = s[tid] - own;             // exclusive suffix sum
  if (tid == 0) curs[0] = 0;
}

__global__ void k2d_scatter(const uint32_t* __restrict__ segs, const uint32_t* __restrict__ nSegs,
                            uint32_t* __restrict__ curs, uint32_t* __restrict__ sorted)
{
  uint32_t i = blockIdx.x*512u + threadIdx.x;
  if (i < *nSegs) {
    uint32_t r = segs[i];
    uint32_t ln = ((r>>19)&1023u) + 1u;
    uint32_t pos = atomicAdd((unsigned int*)&curs[ln], 1u);
    sorted[pos] = r;
  }
}

// ============================================================================
// K3: fused recurrent + heads kernel. 512 thr = 8 waves: wave w -> rt=w&3
// (16-row tile), ch=w>>2 (512 packed gates / head select).
// Per iteration:
//   gates[64x1024] = [x|h][64x384] @ Wp   (MFMA, B-frags register-direct L2)
//   fused LSTM cell (LDS gate exchange, c in regs), h -> A-tile
//   heads: L1 (K=256, h from A-tile) -> tanh -> hb1; L2 -> tanh -> hb2;
//   final 3+1 dots per row (K split over thread pairs), masked store.
// ============================================================================
__global__ __launch_bounds__(512, 2) void k3_lstm_fused(
    const float* __restrict__ x, const int* __restrict__ done,
    const float* __restrict__ h0, const float* __restrict__ c0,
    const short* __restrict__ wpack, const float* __restrict__ bpack,
    const short* __restrict__ wa1p, const short* __restrict__ wv1p,
    const short* __restrict__ wa2p, const short* __restrict__ wv2p,
    const float* __restrict__ ba1, const float* __restrict__ bv1,
    const float* __restrict__ ba2, const float* __restrict__ bv2,
    const float* __restrict__ wa3, const float* __restrict__ ba3,
    const float* __restrict__ wv3, const float* __restrict__ bv3,
    const unsigned char* __restrict__ maskB,
    const uint32_t* __restrict__ maskModePtr,
    const uint32_t* __restrict__ sortedSegs, const uint32_t* __restrict__ nSegsPtr,
    float* __restrict__ logits, float* __restrict__ value,
    float* __restrict__ hnOut, float* __restrict__ cnOut)
{
  __shared__ char smem[123920];
  char* Alds  = smem;                          // 64 rows x 768B (k-bytes, swizzled)
  char* cellB = smem + 49152;                  // 67584B: 8 wave regions x 8448 ([16r][528B])
                                               //   reused post-cell: hb1a@0, hb1v@16K, hb2a@32K, hb2v@48K
  float* biasL = (float*)(smem + 116736);      // 1024 f32
  uint32_t* meta = (uint32_t*)(smem + 120832); // b[64], start[64], len[64]
  float* w3L = (float*)(smem + 121856);        // [4][128]: rows 0-2 Wa3, row 3 Wv3
  float* b3L = (float*)(smem + 123904);        // {ba3_0,ba3_1,ba3_2,bv3}

  const int tid  = threadIdx.x;
  const int lane = tid & 63;
  const int wv   = tid >> 6;
  const int rt   = wv & 3;
  const int ch   = wv >> 2;

  biasL[tid]       = bpack[tid];
  biasL[512 + tid] = bpack[512 + tid];
  if (tid < 128) {
    w3L[tid]       = wa3[tid];
    w3L[128 + tid] = wa3[128 + tid];
    w3L[256 + tid] = wa3[256 + tid];
    w3L[384 + tid] = wv3[tid];
  }
  if (tid == 0) { b3L[0]=ba3[0]; b3L[1]=ba3[1]; b3L[2]=ba3[2]; b3L[3]=bv3[0]; }

  // per-wave head biases into registers (head select by ch)
  float bH1[8], bH2[8];
  {
    const float* b1 = ch ? bv1 : ba1;
    const float* b2 = ch ? bv2 : ba2;
#pragma unroll
    for (int nt=0; nt<8; ++nt) {
      bH1[nt] = b1[nt*16 + (lane&15)];
      bH2[nt] = b2[nt*16 + (lane&15)];
    }
  }
  const short* w1p = ch ? wv1p : wa1p;
  const short* w2p = ch ? wv2p : wa2p;

  const uint32_t maskByteMode = *maskModePtr;  // 1 = 1-byte bools, 0 = int32
  const int* maskI = (const int*)maskB;

  const uint32_t nSegs = *nSegsPtr;
  const uint32_t nGroups = (nSegs + 63u) >> 6;

  for (uint32_t g = blockIdx.x; g < nGroups; g += gridDim.x) {
    __syncthreads();                       // protect prev group state (incl. final-layer reads)
    if (tid < 64) {
      uint32_t idx = g*64u + (uint32_t)tid;
      uint32_t b=0, st=0, ln=0;
      if (idx < nSegs) {
        uint32_t r = sortedSegs[idx];
        b = r & 511u; st = (r>>9)&1023u; ln = ((r>>19)&1023u) + 1u;
      }
      meta[tid] = b; meta[64+tid] = st; meta[128+tid] = ln;
    }
    __syncthreads();

    const int row8 = tid >> 3;             // 0..63 : row this thread owns for x/cell
    const int oct  = tid & 7;
    const uint32_t mb  = meta[row8];
    const uint32_t mst = meta[64+row8];
    const uint32_t mln = meta[128+row8];
    const int maxLen = (int)meta[128];     // slot 0 has group max (desc sort)
    const int rsw = (row8 & 7) << 4;

    // ---- group init: x(iter0) covers [0,256); h covers FULL [256,768) ----
    {
      const bool act = (mln > 0u);
      float xf[16];
      if (act) {
        const float4* xp = (const float4*)(x + ((size_t)mst*512u + mb)*128u + (size_t)oct*16u);
#pragma unroll
        for (int i=0;i<4;++i){ float4 t4 = xp[i]; xf[4*i]=t4.x; xf[4*i+1]=t4.y; xf[4*i+2]=t4.z; xf[4*i+3]=t4.w; }
      } else {
#pragma unroll
        for (int i=0;i<16;++i) xf[i]=0.0f;
      }
      bf16x8 v0, v1;
#pragma unroll
      for (int j=0;j<8;++j){ v0[j]=f2bf(xf[j]); v1[j]=f2bf(xf[8+j]); }
      *(bf16x8*)(Alds + row8*768 + ((oct*32     ) ^ rsw)) = v0;
      *(bf16x8*)(Alds + row8*768 + ((oct*32 + 16) ^ rsw)) = v1;

      const bool useInit = act && (mst == 0u) && (done[mb] == 0);
      float hf[32];
      if (useInit) {
        const float4* hp = (const float4*)(h0 + (size_t)mb*256u + (size_t)oct*32u);
#pragma unroll
        for (int i=0;i<8;++i){ float4 t4 = hp[i]; hf[4*i]=t4.x; hf[4*i+1]=t4.y; hf[4*i+2]=t4.z; hf[4*i+3]=t4.w; }
      } else {
#pragma unroll
        for (int i=0;i<32;++i) hf[i]=0.0f;
      }
#pragma unroll
      for (int q=0;q<4;++q){
        bf16x8 hv;
#pragma unroll
        for (int j=0;j<8;++j) hv[j]=f2bf(hf[q*8+j]);
        *(bf16x8*)(Alds + row8*768 + ((256 + oct*64 + q*16) ^ rsw)) = hv;
      }
    }

    float creg[4][8];
    {
      const bool useInit = (mln > 0u) && (mst == 0u) && (done[mb] == 0);
      const int jsl = oct;
#pragma unroll
      for (int ntg=0; ntg<4; ++ntg) {
        const int j0 = (jsl<4) ? (32*ntg + 8*jsl) : (128 + 32*ntg + 8*(jsl-4));
#pragma unroll
        for (int dj=0; dj<8; ++dj)
          creg[ntg][dj] = useInit ? c0[(size_t)mb*256u + j0 + dj] : 0.0f;
      }
    }

    for (int it = 0; it < maxLen; ++it) {
      __syncthreads();                     // A-tile (x & h) ready

      // ---------------- GEMM: gates = [x|h] @ Wpacked + bias ----------------
      f32x4 acc[32];
#pragma unroll
      for (int nt=0; nt<32; ++nt) {
        float bv = biasL[ch*512 + nt*16 + (lane & 15)];
        f32x4 a = {bv, bv, bv, bv};
        acc[nt] = a;
      }
      const int arow = rt*16 + (lane & 15);
      const int asw  = (arow & 7) << 4;
      const int klane = (lane >> 4) * 16;
      for (int kt=0; kt<12; ++kt) {
        if ((kt & 3) == 0) __builtin_amdgcn_s_barrier();   // wave convergence for L1 frag reuse
        bf16x8 af = *(const bf16x8*)(Alds + arow*768 + ((kt*64 + klane) ^ asw));
        const short* wb = wpack + (size_t)(kt*4 + ch*2)*8192 + lane*8;
#pragma unroll
        for (int nt=0; nt<32; ++nt) {
          const bf16x8 bfr = *(const bf16x8*)(wb + (size_t)(nt>>4)*8192 + (nt&15)*512);
          acc[nt] = __builtin_amdgcn_mfma_f32_16x16x32_bf16(af, bfr, acc[nt], 0, 0, 0);
        }
      }

      // ---------------- prefetch next-step x (bf16 in regs) -----------------
      bf16x8 xpre0, xpre1;
      {
        const bool xact = (it + 1) < (int)mln;
        float xf[16];
        if (xact) {
          const float4* xp = (const float4*)(x + ((size_t)(mst+it+1u)*512u + mb)*128u + (size_t)oct*16u);
#pragma unroll
          for (int i=0;i<4;++i){ float4 t4 = xp[i]; xf[4*i]=t4.x; xf[4*i+1]=t4.y; xf[4*i+2]=t4.z; xf[4*i+3]=t4.w; }
        } else {
#pragma unroll
          for (int i=0;i<16;++i) xf[i]=0.0f;
        }
#pragma unroll
        for (int j=0;j<8;++j){ xpre0[j]=f2bf(xf[j]); xpre1[j]=f2bf(xf[8+j]); }
      }

      // ---------------- fused LSTM cell (4 sub-phases) ----------------------
      const bool cact = it < (int)mln;
#pragma unroll
      for (int ntg=0; ntg<4; ++ntg) {
        __syncthreads();                   // cellBuf free
        {
          char* regn = cellB + wv*8448;
#pragma unroll
          for (int i=0;i<8;++i) {
            const int gsub = i*16 + (lane & 15);
#pragma unroll
            for (int e=0;e<4;++e) {
              const int rloc = (lane>>4)*4 + e;
              *(float*)(regn + rloc*528 + gsub*4) = acc[ntg*8+i][e];
            }
          }
        }
        __syncthreads();
        if (cact) {
          const int jsl = oct;
          const int j0  = (jsl<4) ? (32*ntg + 8*jsl) : (128 + 32*ntg + 8*(jsl-4));
          const int cch = (jsl < 4) ? 0 : 1;
          const char* regn = cellB + (size_t)(cch*4 + (row8>>4))*8448 + (row8 & 15)*528;
          short hp[8]; float hsv[8]; float cns[8];
#pragma unroll
          for (int dj=0; dj<8; ++dj) {
            const int j = j0 + dj;
            const int gsub = 4*(j - 128*cch) - 128*ntg;
            f32x4 gv = *(const f32x4*)(regn + gsub*4);
            float ig = fsig(gv[0]);
            float fg = fsig(gv[1]);
            float gg = ftanh_(gv[2]);
            float og = fsig(gv[3]);
            float c  = fg*creg[ntg][dj] + ig*gg;
            creg[ntg][dj] = c;
            float h = og*ftanh_(c);
            hsv[dj] = h; cns[dj] = c;
            hp[dj] = f2bf(h);
          }
          bf16x8 hv;
#pragma unroll
          for (int dj=0;dj<8;++dj) hv[dj]=hp[dj];
          // h -> A-tile (next-step GEMM operand AND heads-L1 operand)
          *(bf16x8*)(Alds + row8*768 + ((256 + 2*j0) ^ rsw)) = hv;
          // final state of the last segment of this column -> hn/cn (fp32)
          if ((it == (int)mln - 1) && (mst + mln == 1024u)) {
            float4* hp4 = (float4*)(hnOut + (size_t)mb*256u + j0);
            hp4[0] = make_float4(hsv[0],hsv[1],hsv[2],hsv[3]);
            hp4[1] = make_float4(hsv[4],hsv[5],hsv[6],hsv[7]);
            float4* cp4 = (float4*)(cnOut + (size_t)mb*256u + j0);
            cp4[0] = make_float4(cns[0],cns[1],cns[2],cns[3]);
            cp4[1] = make_float4(cns[4],cns[5],cns[6],cns[7]);
          }
        }
      }

      // ---------------- write next x into A-tile (x region only) -----------
      *(bf16x8*)(Alds + row8*768 + ((oct*32     ) ^ rsw)) = xpre0;
      *(bf16x8*)(Alds + row8*768 + ((oct*32 + 16) ^ rsw)) = xpre1;

      __syncthreads();                     // all h writes visible; cellB dead

      // ================= HEADS (fused, per produced h) ======================
      // L1: K=256 from A-tile h region (kt 4..11). ch selects head.
      {
        f32x4 aH[8];
#pragma unroll
        for (int nt=0; nt<8; ++nt) { f32x4 t = {bH1[nt],bH1[nt],bH1[nt],bH1[nt]}; aH[nt] = t; }
        for (int kt2=0; kt2<8; ++kt2) {
          bf16x8 af = *(const bf16x8*)(Alds + arow*768 + (((4+kt2)*64 + klane) ^ asw));
          const short* wb = w1p + (size_t)(kt2*8)*512 + lane*8;
#pragma unroll
          for (int nt=0; nt<8; ++nt) {
            const bf16x8 bfr = *(const bf16x8*)(wb + (size_t)nt*512);
            aH[nt] = __builtin_amdgcn_mfma_f32_16x16x32_bf16(af, bfr, aH[nt], 0,0,0);
          }
        }
        char* hb1 = cellB + ch*16384;
#pragma unroll
        for (int nt=0; nt<8; ++nt) {
#pragma unroll
          for (int e=0;e<4;++e) {
            int row = rt*16 + (lane>>4)*4 + e;
            int sw  = (row&7)<<4;
            int nb  = 2*(nt*16 + (lane&15));
            *(short*)(hb1 + row*256 + (nb ^ sw)) = f2bf(ftanh_(aH[nt][e]));
          }
        }
      }
      __syncthreads();                     // hb1 ready

      // L2: K=128 from hb1
      {
        f32x4 cH[8];
#pragma unroll
        for (int nt=0; nt<8; ++nt) { f32x4 t = {bH2[nt],bH2[nt],bH2[nt],bH2[nt]}; cH[nt] = t; }
        const char* hb1 = cellB + ch*16384;
        for (int kt2=0; kt2<4; ++kt2) {
          bf16x8 af = *(const bf16x8*)(hb1 + arow*256 + ((kt2*64 + klane) ^ asw));
          const short* wb = w2p + (size_t)(kt2*8)*512 + lane*8;
#pragma unroll
          for (int nt=0; nt<8; ++nt) {
            const bf16x8 bfr = *(const bf16x8*)(wb + (size_t)nt*512);
            cH[nt] = __builtin_amdgcn_mfma_f32_16x16x32_bf16(af, bfr, cH[nt], 0,0,0);
          }
        }
        char* hb2 = cellB + 32768 + ch*16384;
#pragma unroll
        for (int nt=0; nt<8; ++nt) {
#pragma unroll
          for (int e=0;e<4;++e) {
            int row = rt*16 + (lane>>4)*4 + e;
            int sw  = (row&7)<<4;
            int nb  = 2*(nt*16 + (lane&15));
            *(short*)(hb2 + row*256 + (nb ^ sw)) = f2bf(ftanh_(cH[nt][e]));
          }
        }
      }
      __syncthreads();                     // hb2 ready

      // Final layer: 64 rows x 4 outs x 2 K-halves = 512 threads
      {
        const int frow = tid >> 3;
        const int o    = (tid >> 1) & 3;
        const int half = tid & 1;
        const uint32_t fmb  = meta[frow];
        const uint32_t fmst = meta[64+frow];
        const uint32_t fmln = meta[128+frow];
        const char* srcb = (o < 3) ? (cellB + 32768) : (cellB + 49152);
        const int sw = (frow&7)<<4;
        float s = half ? 0.0f : b3L[o];
        const float* wr = w3L + o*128 + half*64;
#pragma unroll
        for (int k16=0; k16<8; ++k16) {
          bf16x8 av = *(const bf16x8*)(srcb + frow*256 + (((half*8 + k16)*16) ^ sw));
#pragma unroll
          for (int j=0;j<8;++j) s += bf2f(av[j]) * wr[k16*8+j];
        }
        s += __shfl_xor(s, 1);
        if (half == 0 && it < (int)fmln) {
          const size_t grow = (size_t)((int)fmst + it)*512u + fmb;
          if (o < 3) {
            const size_t mi = grow*3u + (size_t)o;
            const bool masked = maskByteMode ? (maskB[mi] != 0) : (maskI[mi] != 0);
            logits[mi] = masked ? -1e8f : s;
          } else {
            value[grow] = s;
          }
        }
      }
      // no trailing barrier: loop-top __syncthreads orders hb2 reads vs
      // next iteration's cellB writes (two barriers in between)
    }
  }
}

// ============================================================================
extern "C" void kernel_launch(void* const* d_in, const int* in_sizes, int n_in,
                              void* d_out, int out_size, void* d_ws, size_t ws_size,
                              hipStream_t stream) {
  const float* x    = (const float*)d_in[0];
  const int*   done = (const int*)d_in[1];
  const unsigned char* mask = (const unsigned char*)d_in[2];
  const float* h0   = (const float*)d_in[3];
  const float* c0   = (const float*)d_in[4];
  const float* wih  = (const float*)d_in[5];
  const float* whh  = (const float*)d_in[6];
  const float* bih  = (const float*)d_in[7];
  const float* bhh  = (const float*)d_in[8];
  const float* wa1  = (const float*)d_in[9];
  const float* ba1  = (const float*)d_in[10];
  const float* wa2  = (const float*)d_in[11];
  const float* ba2  = (const float*)d_in[12];
  const float* wa3  = (const float*)d_in[13];
  const float* ba3  = (const float*)d_in[14];
  const float* wv1  = (const float*)d_in[15];
  const float* bv1  = (const float*)d_in[16];
  const float* wv2  = (const float*)d_in[17];
  const float* bv2  = (const float*)d_in[18];
  const float* wv3  = (const float*)d_in[19];
  const float* bv3  = (const float*)d_in[20];

  char* ws = (char*)d_ws;
  float* outLogits = (float*)d_out;                 // 524288*3
  float* outValue  = outLogits + 1572864;           // 524288
  float* outHn     = outValue  + 524288;            // 131072
  float* outCn     = outHn     + 131072;            // 131072
  // ws use: 5,275,648 bytes total

  hipMemsetAsync(ws + WS_META, 0, 16384, stream);   // nSegs + maskMode + histogram

  k0a_packmain<<<96, 512, 0, stream>>>(wih, whh, bih, bhh,
      (short*)(ws + WS_WMAIN), (float*)(ws + WS_BMAIN));
  k0b_packheads<<<24, 512, 0, stream>>>(wa1, wv1, wa2, wv2,
      (short*)(ws + WS_WA1P), (short*)(ws + WS_WV1P),
      (short*)(ws + WS_WA2P), (short*)(ws + WS_WV2P));

  k1_maskmode<<<64, 256, 0, stream>>>(mask, (uint32_t*)(ws + WS_META + 16));

  k2a_segments<<<512, 256, 0, stream>>>(done, (uint32_t*)(ws + WS_SEGS),
                                        (uint32_t*)(ws + WS_META));
  k2b_hist<<<1024, 512, 0, stream>>>((const uint32_t*)(ws + WS_SEGS),
      (const uint32_t*)(ws + WS_META), (uint32_t*)(ws + WS_META + 4096));
  k2c_scan<<<1, 1024, 0, stream>>>((const uint32_t*)(ws + WS_META + 4096),
      (uint32_t*)(ws + WS_META + 12288));
  k2d_scatter<<<1024, 512, 0, stream>>>((const uint32_t*)(ws + WS_SEGS),
      (const uint32_t*)(ws + WS_META), (uint32_t*)(ws + WS_META + 12288),
      (uint32_t*)(ws + WS_SORTED));

  k3_lstm_fused<<<256, 512, 0, stream>>>(x, done, h0, c0,
      (const short*)(ws + WS_WMAIN), (const float*)(ws + WS_BMAIN),
      (const short*)(ws + WS_WA1P), (const short*)(ws + WS_WV1P),
      (const short*)(ws + WS_WA2P), (const short*)(ws + WS_WV2P),
      ba1, bv1, ba2, bv2, wa3, ba3, wv3, bv3,
      mask, (const uint32_t*)(ws + WS_META + 16),
      (const uint32_t*)(ws + WS_SORTED), (const uint32_t*)(ws + WS_META),
      outLogits, outValue, outHn, outCn);

  (void)in_sizes; (void)n_in; (void)out_size; (void)ws_size;
}

// Round 4
// 6147.788 us; speedup vs baseline: 1.7817x; 1.7817x over previous
//
#include <hip/hip_runtime.h>
#include <hip/hip_bf16.h>
#include <stdint.h>
#include <stddef.h>

// ============================================================================
// PPOAgent fused pipeline for MI355X (gfx950) — v4
// LSTM(1024,BS=512,IN=128,H=256) + both MLP heads fused in one kernel.
// v4 change vs R3: OPERAND-SWAPPED GEMM — C[gates][rows] = mfma(W_frag, row_frag).
// With gate packing cgp = gq*256 + nt*16 + u*4 + e, each lane's acc[nt][0..3]
// = (i,f,g,o) of ONE cell -> no LDS gate exchange, no 8 barriers, and per-wave
// acc halves to 2x16 f32x4 with total live ~230 regs < 256 budget (no spill).
// ============================================================================

typedef short bf16x8 __attribute__((ext_vector_type(8)));
typedef short bf16x4 __attribute__((ext_vector_type(4)));
typedef float f32x4  __attribute__((ext_vector_type(4)));

#define LOG2E 1.44269504088896340736f

__device__ __forceinline__ float fexp2(float x){ return __builtin_amdgcn_exp2f(x); }
__device__ __forceinline__ float frcpf_(float x){ return __builtin_amdgcn_rcpf(x); }
__device__ __forceinline__ float fsig(float x){ return frcpf_(1.0f + fexp2(-x*LOG2E)); }
__device__ __forceinline__ float ftanh_(float x){ return 1.0f - 2.0f*frcpf_(1.0f + fexp2(x*(2.0f*LOG2E))); }

__device__ __forceinline__ short f2bf(float f){
  unsigned u = __builtin_bit_cast(unsigned, f);
  u += 0x7fffu + ((u>>16)&1u);
  return (short)(u>>16);
}
__device__ __forceinline__ float bf2f(short h){
  unsigned u = ((unsigned)(unsigned short)h)<<16;
  return __builtin_bit_cast(float, u);
}

// ---------------- workspace layout (bytes); total ~5.3 MB ----------------
static constexpr size_t WS_WMAIN  = 0;          // packed [Wih;Whh] A-frag stream, 384x1024 bf16 = 786432
static constexpr size_t WS_WA1P   = 786432;     // 65536
static constexpr size_t WS_WV1P   = 851968;     // 65536
static constexpr size_t WS_WA2P   = 917504;     // 32768
static constexpr size_t WS_WV2P   = 950272;     // 32768
static constexpr size_t WS_BMAIN  = 983040;     // 1024 f32 packed-order bias
static constexpr size_t WS_META   = 1048576;    // nSegs@+0 ; maskMode@+16 ; hist@+4096 ; curs@+12288
static constexpr size_t WS_SEGS   = 1081344;    // 524288 u32
static constexpr size_t WS_SORTED = 3178496;    // 524288 u32  (end: 5275648)

// ============================================================================
// K0a: pack [W_ih; W_hh] as MFMA A-fragment stream + packed-order bias.
// Packed gate index cgp = gq*256 + nt*16 + u*4 + e :
//   j = gq*64 + u*16 + nt (h index), e = gate type (i,f,g,o), g = e*256 + j.
// Chunk (kt, gq): addr(short) = (kt*4+gq)*8192 + nt*512 + lane*8
// A-frag (16x16x32): lane&15 = A-row (= gate slot u*4+e), k = kt*32+(lane>>4)*8+jj
// ============================================================================
__global__ void k0a_packmain(const float* __restrict__ wih, const float* __restrict__ whh,
                             const float* __restrict__ bih, const float* __restrict__ bhh,
                             short* __restrict__ wp, float* __restrict__ bp)
{
  int tidg = blockIdx.x*512 + threadIdx.x;     // 0..49151
  {
    int lane = tidg & 63;
    int nt   = (tidg>>6) & 15;
    int ci   = tidg>>10;                       // 0..47
    int kt = ci>>2, gq = ci&3;
    int gs = lane & 15;
    int ug = gs>>2, eg = gs&3;
    int j  = gq*64 + ug*16 + nt;
    int g  = eg*256 + j;
    int k0 = kt*32 + (lane>>4)*8;
    bf16x8 ov;
#pragma unroll
    for (int jj=0;jj<8;++jj){
      int k = k0 + jj;
      float v = (k < 128) ? wih[(size_t)g*128 + k] : whh[(size_t)g*256 + (k-128)];
      ov[jj] = f2bf(v);
    }
    *(bf16x8*)(wp + (size_t)tidg*8) = ov;
  }
  if (tidg < 1024) {
    int cgp = tidg;
    int gq = cgp>>8, nt = (cgp>>4)&15, ug = (cgp>>2)&3, eg = cgp&3;
    int g = eg*256 + gq*64 + ug*16 + nt;
    bp[cgp] = bih[g] + bhh[g];
  }
}

// K0b: pack head weights (N x K row-major -> frag stream; same per-lane formula
// works as A-frag or B-frag). addr = (kt*8+ntile)*512 + lane*8 shorts.
__global__ void k0b_packheads(const float* __restrict__ wa1, const float* __restrict__ wv1,
                              const float* __restrict__ wa2, const float* __restrict__ wv2,
                              short* __restrict__ wa1p, short* __restrict__ wv1p,
                              short* __restrict__ wa2p, short* __restrict__ wv2p)
{
  int p = blockIdx.x*512 + threadIdx.x;     // 0..12287
  const float* src; short* dst; int K; int pl;
  if (p < 4096)       { src=wa1; dst=wa1p; K=256; pl=p; }
  else if (p < 8192)  { src=wv1; dst=wv1p; K=256; pl=p-4096; }
  else if (p < 10240) { src=wa2; dst=wa2p; K=128; pl=p-8192; }
  else                { src=wv2; dst=wv2p; K=128; pl=p-10240; }
  int lane = pl & 63;
  int f    = pl >> 6;
  int nt   = f & 7;
  int kt   = f >> 3;
  int n  = nt*16 + (lane&15);
  int k0 = kt*32 + (lane>>4)*8;
  bf16x8 ov;
#pragma unroll
  for (int j=0;j<8;++j) ov[j] = f2bf(src[(size_t)n*K + k0 + j]);
  *(bf16x8*)(dst + (size_t)pl*8) = ov;
}

// K1: detect mask storage layout (byte-bools vs int32), see R3 notes.
__global__ void k1_maskmode(const unsigned char* __restrict__ mask, uint32_t* __restrict__ flag)
{
  int i = blockIdx.x*256 + threadIdx.x;
  uint32_t v = ((i & 3) != 0) ? (uint32_t)mask[i] : 0u;
  if (v) atomicOr((unsigned int*)flag, 1u);
}

// ============================================================================
// K2a-d: segment extraction + bucket sort by length (descending). Unchanged.
// ============================================================================
__global__ void k2a_segments(const int* __restrict__ done, uint32_t* __restrict__ segs,
                             uint32_t* __restrict__ nSegs)
{
  const int b = blockIdx.x;
  const int tid = threadIdx.x;
  __shared__ uint16_t starts[1025];
  __shared__ uint32_t cnts[256];
  __shared__ uint32_t basePos;

  uint32_t my[4]; int myn = 0;
  int t0 = tid*4;
#pragma unroll
  for (int i=0;i<4;++i){
    int t = t0 + i;
    int d = done[(size_t)t*512 + b];
    if (t == 0 || d != 0) my[myn++] = (uint32_t)t;
  }
  cnts[tid] = (uint32_t)myn;
  __syncthreads();
  for (int off=1; off<256; off<<=1){
    uint32_t v = (tid >= off) ? cnts[tid-off] : 0u;
    __syncthreads();
    cnts[tid] += v;
    __syncthreads();
  }
  uint32_t myBase = cnts[tid] - (uint32_t)myn;
  uint32_t ns = cnts[255];
  for (int i=0;i<myn;++i) starts[myBase+i] = (uint16_t)my[i];
  if (tid == 0) {
    starts[ns] = 1024;
    basePos = atomicAdd((unsigned int*)nSegs, ns);
  }
  __syncthreads();
  for (uint32_t i = tid; i < ns; i += 256) {
    uint32_t st = starts[i];
    uint32_t ln = (uint32_t)starts[i+1] - st;
    segs[basePos + i] = ((ln-1u)<<19) | (st<<9) | (uint32_t)b;
  }
}

__global__ void k2b_hist(const uint32_t* __restrict__ segs, const uint32_t* __restrict__ nSegs,
                         uint32_t* __restrict__ hist)
{
  uint32_t i = blockIdx.x*512u + threadIdx.x;
  if (i < *nSegs) {
    uint32_t ln = ((segs[i]>>19)&1023u) + 1u;
    atomicAdd((unsigned int*)&hist[ln], 1u);
  }
}

__global__ void k2c_scan(const uint32_t* __restrict__ hist, uint32_t* __restrict__ curs)
{
  __shared__ uint32_t s[1024];
  const int tid = threadIdx.x;
  uint32_t own = hist[tid+1];
  s[tid] = own;
  __syncthreads();
  for (int off=1; off<1024; off<<=1){
    uint32_t v = (tid+off < 1024) ? s[tid+off] : 0u;
    __syncthreads();
    s[tid] += v;
    __syncthreads();
  }
  curs[tid+1] = s[tid] - own;
  if (tid == 0) curs[0] = 0;
}

__global__ void k2d_scatter(const uint32_t* __restrict__ segs, const uint32_t* __restrict__ nSegs,
                            uint32_t* __restrict__ curs, uint32_t* __restrict__ sorted)
{
  uint32_t i = blockIdx.x*512u + threadIdx.x;
  if (i < *nSegs) {
    uint32_t r = segs[i];
    uint32_t ln = ((r>>19)&1023u) + 1u;
    uint32_t pos = atomicAdd((unsigned int*)&curs[ln], 1u);
    sorted[pos] = r;
  }
}

// ============================================================================
// K3 v4: 512 thr = 8 waves = (gq in [0,4)) x (rh in {0,1}).
// Wave computes gates[gq*256..+256) x rows[rh*32..+32) via acc[2][16];
// lane (cl=lane&15, u=lane>>4): rows rA=rh*32+cl, rB=rA+16;
// acc{A,B}[nt][e] = gate type e for j = gq*64+u*16+nt  -> cell is per-lane.
// LDS: A-tile [64][768B] swz ^(row&7)<<4 ; hb1/hb2 2 heads x [64][256B].
// ============================================================================
__global__ __launch_bounds__(512, 2) void k3_lstm_fused(
    const float* __restrict__ x, const int* __restrict__ done,
    const float* __restrict__ h0, const float* __restrict__ c0,
    const short* __restrict__ wpack, const float* __restrict__ bpack,
    const short* __restrict__ wa1p, const short* __restrict__ wv1p,
    const short* __restrict__ wa2p, const short* __restrict__ wv2p,
    const float* __restrict__ ba1, const float* __restrict__ bv1,
    const float* __restrict__ ba2, const float* __restrict__ bv2,
    const float* __restrict__ wa3, const float* __restrict__ ba3,
    const float* __restrict__ wv3, const float* __restrict__ bv3,
    const unsigned char* __restrict__ maskB,
    const uint32_t* __restrict__ maskModePtr,
    const uint32_t* __restrict__ sortedSegs, const uint32_t* __restrict__ nSegsPtr,
    float* __restrict__ logits, float* __restrict__ value,
    float* __restrict__ hnOut, float* __restrict__ cnOut)
{
  __shared__ char smem[121616];
  char* Alds = smem;                            // [64][768] swizzled
  char* hb1  = smem + 49152;                    // 2 x [64][256] (head-major)
  char* hb2  = smem + 81920;                    // 2 x [64][256]
  float* biasL = (float*)(smem + 114688);       // 1024 f32 (packed order)
  uint32_t* meta = (uint32_t*)(smem + 118784);  // b[64], start[64], len[64]
  float* w3L = (float*)(smem + 119552);         // [4][128]: Wa3 rows 0-2, Wv3 row 3
  float* b3L = (float*)(smem + 121600);         // {ba3_0,ba3_1,ba3_2,bv3}

  const int tid  = threadIdx.x;
  const int lane = tid & 63;
  const int wv   = tid >> 6;
  const int gq   = wv & 3;          // gate quarter
  const int hd   = wv >> 2;         // also: row half + head select
  const int cl   = lane & 15;
  const int u    = lane >> 4;
  const int ku   = u*16;            // k-slice byte offset
  const int swc  = (cl & 7) << 4;   // row swizzle (rA&7 == rB&7 == cl&7)
  const int rA   = hd*32 + cl;
  const int rB   = rA + 16;
  const int jb   = gq*64 + u*16;    // this lane's h-index base
  const int jb2  = 2*jb;            // ...as bytes

  // x/init path decomposition (per-thread row ownership)
  const int row8 = tid >> 3;
  const int oct  = tid & 7;
  const int rsw8 = (row8 & 7) << 4;

  biasL[tid]       = bpack[tid];
  biasL[512 + tid] = bpack[512 + tid];
  if (tid < 128) {
    w3L[tid]       = wa3[tid];
    w3L[128 + tid] = wa3[128 + tid];
    w3L[256 + tid] = wa3[256 + tid];
    w3L[384 + tid] = wv3[tid];
  }
  if (tid == 0) { b3L[0]=ba3[0]; b3L[1]=ba3[1]; b3L[2]=ba3[2]; b3L[3]=bv3[0]; }

  // head biases (hoisted; head = hd)
  float4 bH1v[2], bH2v[2];
  {
    const float* b1 = hd ? bv1 : ba1;
    const float* b2 = hd ? bv2 : ba2;
#pragma unroll
    for (int n1=0; n1<2; ++n1) {
      bH1v[n1] = *(const float4*)(b1 + gq*32 + n1*16 + u*4);
      bH2v[n1] = *(const float4*)(b2 + gq*32 + n1*16 + u*4);
    }
  }
  const short* w1p = hd ? wv1p : wa1p;
  const short* w2p = hd ? wv2p : wa2p;

  const uint32_t maskByteMode = *maskModePtr;
  const int* maskI = (const int*)maskB;

  const uint32_t nSegs = *nSegsPtr;
  const uint32_t nGroups = (nSegs + 63u) >> 6;

  for (uint32_t g = blockIdx.x; g < nGroups; g += gridDim.x) {
    __syncthreads();                       // prev group fully consumed
    if (tid < 64) {
      uint32_t idx = g*64u + (uint32_t)tid;
      uint32_t b=0, st=0, ln=0;
      if (idx < nSegs) {
        uint32_t r = sortedSegs[idx];
        b = r & 511u; st = (r>>9)&1023u; ln = ((r>>19)&1023u) + 1u;
      }
      meta[tid] = b; meta[64+tid] = st; meta[128+tid] = ln;
    }
    __syncthreads();

    // per-thread segment meta
    const uint32_t mb8  = meta[row8];
    const uint32_t mst8 = meta[64+row8];
    const uint32_t mln8 = meta[128+row8];
    const uint32_t mbA  = meta[rA],    mbB  = meta[rB];
    const uint32_t mstA = meta[64+rA], mstB = meta[64+rB];
    const uint32_t mlnA = meta[128+rA],mlnB = meta[128+rB];
    const int maxLen = (int)meta[128];   // desc sort -> slot 0 max

    // ---- group init: x(iter0) [0,256) + FULL h [256,768) into A-tile ----
    {
      const bool act = (mln8 > 0u);
      float xf[16];
      if (act) {
        const float4* xp = (const float4*)(x + ((size_t)mst8*512u + mb8)*128u + (size_t)oct*16u);
#pragma unroll
        for (int i=0;i<4;++i){ float4 t4 = xp[i]; xf[4*i]=t4.x; xf[4*i+1]=t4.y; xf[4*i+2]=t4.z; xf[4*i+3]=t4.w; }
      } else {
#pragma unroll
        for (int i=0;i<16;++i) xf[i]=0.0f;
      }
      bf16x8 v0, v1;
#pragma unroll
      for (int j=0;j<8;++j){ v0[j]=f2bf(xf[j]); v1[j]=f2bf(xf[8+j]); }
      *(bf16x8*)(Alds + row8*768 + ((oct*32     ) ^ rsw8)) = v0;
      *(bf16x8*)(Alds + row8*768 + ((oct*32 + 16) ^ rsw8)) = v1;

      const bool useInit = act && (mst8 == 0u) && (done[mb8] == 0);
      float hf[32];
      if (useInit) {
        const float4* hp = (const float4*)(h0 + (size_t)mb8*256u + (size_t)oct*32u);
#pragma unroll
        for (int i=0;i<8;++i){ float4 t4 = hp[i]; hf[4*i]=t4.x; hf[4*i+1]=t4.y; hf[4*i+2]=t4.z; hf[4*i+3]=t4.w; }
      } else {
#pragma unroll
        for (int i=0;i<32;++i) hf[i]=0.0f;
      }
#pragma unroll
      for (int q=0;q<4;++q){
        bf16x8 hv;
#pragma unroll
        for (int j=0;j<8;++j) hv[j]=f2bf(hf[q*8+j]);
        *(bf16x8*)(Alds + row8*768 + ((256 + oct*64 + q*16) ^ rsw8)) = hv;
      }
    }

    // ---- c state init (per-lane rows rA/rB, j = jb + nt) ----
    float cregA[16], cregB[16];
    {
      const bool initA = (mlnA > 0u) && (mstA == 0u) && (done[mbA] == 0);
      const bool initB = (mlnB > 0u) && (mstB == 0u) && (done[mbB] == 0);
      f32x4 ca[4], cb[4];
#pragma unroll
      for (int q=0;q<4;++q){
        ca[q] = initA ? *(const f32x4*)(c0 + (size_t)mbA*256u + jb + q*4) : (f32x4){0.f,0.f,0.f,0.f};
        cb[q] = initB ? *(const f32x4*)(c0 + (size_t)mbB*256u + jb + q*4) : (f32x4){0.f,0.f,0.f,0.f};
      }
#pragma unroll
      for (int nt=0;nt<16;++nt){ cregA[nt]=ca[nt>>2][nt&3]; cregB[nt]=cb[nt>>2][nt&3]; }
    }

    for (int it = 0; it < maxLen; ++it) {
      __syncthreads();                   // S1: A-tile (x,h) ready

      // ---------- GEMM: C[gates][rows] = Wp @ [x|h]^T + bias ----------
      f32x4 accA[16], accB[16];
#pragma unroll
      for (int nt=0;nt<16;++nt){
        f32x4 bv = *(const f32x4*)(biasL + gq*256 + nt*16 + u*4);
        accA[nt]=bv; accB[nt]=bv;
      }
      for (int kt=0; kt<12; ++kt) {
        if ((kt & 3) == 0) __builtin_amdgcn_s_barrier();   // wave convergence (L1 frag reuse)
        const short* wkt = wpack + (size_t)(kt*4 + gq)*8192 + lane*8;
        bf16x8 bfA = *(const bf16x8*)(Alds + rA*768 + ((kt*64 + ku) ^ swc));
        bf16x8 bfB = *(const bf16x8*)(Alds + rB*768 + ((kt*64 + ku) ^ swc));
#pragma unroll
        for (int nt=0;nt<16;++nt) {
          const bf16x8 wf = *(const bf16x8*)(wkt + nt*512);
          accA[nt] = __builtin_amdgcn_mfma_f32_16x16x32_bf16(wf, bfA, accA[nt], 0,0,0);
          accB[nt] = __builtin_amdgcn_mfma_f32_16x16x32_bf16(wf, bfB, accB[nt], 0,0,0);
        }
      }

      // ---------- x prefetch for it+1 (regs; consumed after S2) ----------
      float4 xq0,xq1,xq2,xq3;
      {
        const bool xact = (it + 1) < (int)mln8;
        if (xact) {
          const float4* xp = (const float4*)(x + ((size_t)(mst8+it+1u)*512u + mb8)*128u + (size_t)oct*16u);
          xq0=xp[0]; xq1=xp[1]; xq2=xp[2]; xq3=xp[3];
        } else {
          xq0=xq1=xq2=xq3=make_float4(0.f,0.f,0.f,0.f);
        }
      }

      __syncthreads();                   // S2: all GEMM reads done; A-tile writable

      // ---------- LSTM cell: pure per-lane registers ----------
      float hfA[16], hfB[16];
#pragma unroll
      for (int nt=0;nt<16;++nt) {
        f32x4 gA = accA[nt];
        float i0=fsig(gA[0]), f0=fsig(gA[1]), g0=ftanh_(gA[2]), o0=fsig(gA[3]);
        float cA = f0*cregA[nt] + i0*g0; cregA[nt]=cA; hfA[nt] = o0*ftanh_(cA);
        f32x4 gB = accB[nt];
        float i1=fsig(gB[0]), f1=fsig(gB[1]), g1=ftanh_(gB[2]), o1=fsig(gB[3]);
        float cB = f1*cregB[nt] + i1*g1; cregB[nt]=cB; hfB[nt] = o1*ftanh_(cB);
      }
      {
        bf16x8 hv0, hv1;
#pragma unroll
        for (int q=0;q<8;++q){ hv0[q]=f2bf(hfA[q]); hv1[q]=f2bf(hfA[8+q]); }
        *(bf16x8*)(Alds + rA*768 + ((256 + jb2     ) ^ swc)) = hv0;
        *(bf16x8*)(Alds + rA*768 + ((256 + jb2 + 16) ^ swc)) = hv1;
#pragma unroll
        for (int q=0;q<8;++q){ hv0[q]=f2bf(hfB[q]); hv1[q]=f2bf(hfB[8+q]); }
        *(bf16x8*)(Alds + rB*768 + ((256 + jb2     ) ^ swc)) = hv0;
        *(bf16x8*)(Alds + rB*768 + ((256 + jb2 + 16) ^ swc)) = hv1;
      }
      // final LSTM state of each column -> hn/cn (rare path)
      if ((it == (int)mlnA - 1) && (mstA + mlnA == 1024u)) {
        float4* hp4 = (float4*)(hnOut + (size_t)mbA*256u + jb);
        float4* cp4 = (float4*)(cnOut + (size_t)mbA*256u + jb);
#pragma unroll
        for (int q=0;q<4;++q){
          hp4[q] = make_float4(hfA[4*q],hfA[4*q+1],hfA[4*q+2],hfA[4*q+3]);
          cp4[q] = make_float4(cregA[4*q],cregA[4*q+1],cregA[4*q+2],cregA[4*q+3]);
        }
      }
      if ((it == (int)mlnB - 1) && (mstB + mlnB == 1024u)) {
        float4* hp4 = (float4*)(hnOut + (size_t)mbB*256u + jb);
        float4* cp4 = (float4*)(cnOut + (size_t)mbB*256u + jb);
#pragma unroll
        for (int q=0;q<4;++q){
          hp4[q] = make_float4(hfB[4*q],hfB[4*q+1],hfB[4*q+2],hfB[4*q+3]);
          cp4[q] = make_float4(cregB[4*q],cregB[4*q+1],cregB[4*q+2],cregB[4*q+3]);
        }
      }
      // next-step x into A-tile
      {
        float xf[16];
        xf[0]=xq0.x; xf[1]=xq0.y; xf[2]=xq0.z; xf[3]=xq0.w;
        xf[4]=xq1.x; xf[5]=xq1.y; xf[6]=xq1.z; xf[7]=xq1.w;
        xf[8]=xq2.x; xf[9]=xq2.y; xf[10]=xq2.z; xf[11]=xq2.w;
        xf[12]=xq3.x; xf[13]=xq3.y; xf[14]=xq3.z; xf[15]=xq3.w;
        bf16x8 v0, v1;
#pragma unroll
        for (int j=0;j<8;++j){ v0[j]=f2bf(xf[j]); v1[j]=f2bf(xf[8+j]); }
        *(bf16x8*)(Alds + row8*768 + ((oct*32     ) ^ rsw8)) = v0;
        *(bf16x8*)(Alds + row8*768 + ((oct*32 + 16) ^ rsw8)) = v1;
      }

      __syncthreads();                   // S3: h writes visible

      // ========== HEADS: L1 (K=256), head = hd, n-slice = gq*32..+32 ==========
      {
        f32x4 h1[2][4];
#pragma unroll
        for (int n1=0;n1<2;++n1){
          f32x4 bv = {bH1v[n1].x, bH1v[n1].y, bH1v[n1].z, bH1v[n1].w};
#pragma unroll
          for (int r4=0;r4<4;++r4) h1[n1][r4] = bv;
        }
        for (int kt2=0; kt2<8; ++kt2) {
          bf16x8 bh[4];
#pragma unroll
          for (int r4=0;r4<4;++r4)
            bh[r4] = *(const bf16x8*)(Alds + (r4*16+cl)*768 + ((256 + kt2*64 + ku) ^ swc));
#pragma unroll
          for (int n1=0;n1<2;++n1) {
            const bf16x8 wf = *(const bf16x8*)(w1p + (size_t)(kt2*8 + gq*2 + n1)*512 + lane*8);
#pragma unroll
            for (int r4=0;r4<4;++r4)
              h1[n1][r4] = __builtin_amdgcn_mfma_f32_16x16x32_bf16(wf, bh[r4], h1[n1][r4], 0,0,0);
          }
        }
        char* hb = hb1 + hd*16384;
#pragma unroll
        for (int n1=0;n1<2;++n1){
#pragma unroll
          for (int r4=0;r4<4;++r4){
            bf16x4 hv;
#pragma unroll
            for (int e=0;e<4;++e) hv[e] = f2bf(ftanh_(h1[n1][r4][e]));
            int row = r4*16 + cl;
            *(bf16x4*)(hb + row*256 + ((2*(gq*32 + n1*16 + u*4)) ^ swc)) = hv;
          }
        }
      }
      __syncthreads();                   // S4: hb1 ready

      // ========== HEADS: L2 (K=128) ==========
      {
        f32x4 h2[2][4];
#pragma unroll
        for (int n1=0;n1<2;++n1){
          f32x4 bv = {bH2v[n1].x, bH2v[n1].y, bH2v[n1].z, bH2v[n1].w};
#pragma unroll
          for (int r4=0;r4<4;++r4) h2[n1][r4] = bv;
        }
        const char* hbIn = hb1 + hd*16384;
        for (int kt2=0; kt2<4; ++kt2) {
          bf16x8 bh[4];
#pragma unroll
          for (int r4=0;r4<4;++r4)
            bh[r4] = *(const bf16x8*)(hbIn + (r4*16+cl)*256 + ((kt2*64 + ku) ^ swc));
#pragma unroll
          for (int n1=0;n1<2;++n1) {
            const bf16x8 wf = *(const bf16x8*)(w2p + (size_t)(kt2*8 + gq*2 + n1)*512 + lane*8);
#pragma unroll
            for (int r4=0;r4<4;++r4)
              h2[n1][r4] = __builtin_amdgcn_mfma_f32_16x16x32_bf16(wf, bh[r4], h2[n1][r4], 0,0,0);
          }
        }
        char* hb = hb2 + hd*16384;
#pragma unroll
        for (int n1=0;n1<2;++n1){
#pragma unroll
          for (int r4=0;r4<4;++r4){
            bf16x4 hv;
#pragma unroll
            for (int e=0;e<4;++e) hv[e] = f2bf(ftanh_(h2[n1][r4][e]));
            int row = r4*16 + cl;
            *(bf16x4*)(hb + row*256 + ((2*(gq*32 + n1*16 + u*4)) ^ swc)) = hv;
          }
        }
      }
      __syncthreads();                   // S5: hb2 ready

      // ========== final layer: 64 rows x 4 outs x 2 K-halves ==========
      {
        const int frow = tid >> 3;
        const int o    = (tid >> 1) & 3;
        const int half = tid & 1;
        const uint32_t fmb  = meta[frow];
        const uint32_t fmst = meta[64+frow];
        const uint32_t fmln = meta[128+frow];
        const char* srcb = (o < 3) ? hb2 : (hb2 + 16384);
        const int sw = (frow&7)<<4;
        float s = half ? 0.0f : b3L[o];
        const float* wr = w3L + o*128 + half*64;
#pragma unroll
        for (int k16=0; k16<8; ++k16) {
          bf16x8 av = *(const bf16x8*)(srcb + frow*256 + (((half*8 + k16)*16) ^ sw));
#pragma unroll
          for (int j=0;j<8;++j) s += bf2f(av[j]) * wr[k16*8+j];
        }
        s += __shfl_xor(s, 1);
        if (half == 0 && it < (int)fmln) {
          const size_t grow = (size_t)((int)fmst + it)*512u + fmb;
          if (o < 3) {
            const size_t mi = grow*3u + (size_t)o;
            const bool masked = maskByteMode ? (maskB[mi] != 0) : (maskI[mi] != 0);
            logits[mi] = masked ? -1e8f : s;
          } else {
            value[grow] = s;
          }
        }
      }
      // loop-top S1 orders next iteration vs these reads
    }
  }
}

// ============================================================================
extern "C" void kernel_launch(void* const* d_in, const int* in_sizes, int n_in,
                              void* d_out, int out_size, void* d_ws, size_t ws_size,
                              hipStream_t stream) {
  const float* x    = (const float*)d_in[0];
  const int*   done = (const int*)d_in[1];
  const unsigned char* mask = (const unsigned char*)d_in[2];
  const float* h0   = (const float*)d_in[3];
  const float* c0   = (const float*)d_in[4];
  const float* wih  = (const float*)d_in[5];
  const float* whh  = (const float*)d_in[6];
  const float* bih  = (const float*)d_in[7];
  const float* bhh  = (const float*)d_in[8];
  const float* wa1  = (const float*)d_in[9];
  const float* ba1  = (const float*)d_in[10];
  const float* wa2  = (const float*)d_in[11];
  const float* ba2  = (const float*)d_in[12];
  const float* wa3  = (const float*)d_in[13];
  const float* ba3  = (const float*)d_in[14];
  const float* wv1  = (const float*)d_in[15];
  const float* bv1  = (const float*)d_in[16];
  const float* wv2  = (const float*)d_in[17];
  const float* bv2  = (const float*)d_in[18];
  const float* wv3  = (const float*)d_in[19];
  const float* bv3  = (const float*)d_in[20];

  char* ws = (char*)d_ws;
  float* outLogits = (float*)d_out;                 // 524288*3
  float* outValue  = outLogits + 1572864;           // 524288
  float* outHn     = outValue  + 524288;            // 131072
  float* outCn     = outHn     + 131072;            // 131072

  hipMemsetAsync(ws + WS_META, 0, 16384, stream);   // nSegs + maskMode + histogram

  k0a_packmain<<<96, 512, 0, stream>>>(wih, whh, bih, bhh,
      (short*)(ws + WS_WMAIN), (float*)(ws + WS_BMAIN));
  k0b_packheads<<<24, 512, 0, stream>>>(wa1, wv1, wa2, wv2,
      (short*)(ws + WS_WA1P), (short*)(ws + WS_WV1P),
      (short*)(ws + WS_WA2P), (short*)(ws + WS_WV2P));

  k1_maskmode<<<64, 256, 0, stream>>>(mask, (uint32_t*)(ws + WS_META + 16));

  k2a_segments<<<512, 256, 0, stream>>>(done, (uint32_t*)(ws + WS_SEGS),
                                        (uint32_t*)(ws + WS_META));
  k2b_hist<<<1024, 512, 0, stream>>>((const uint32_t*)(ws + WS_SEGS),
      (const uint32_t*)(ws + WS_META), (uint32_t*)(ws + WS_META + 4096));
  k2c_scan<<<1, 1024, 0, stream>>>((const uint32_t*)(ws + WS_META + 4096),
      (uint32_t*)(ws + WS_META + 12288));
  k2d_scatter<<<1024, 512, 0, stream>>>((const uint32_t*)(ws + WS_SEGS),
      (const uint32_t*)(ws + WS_META), (uint32_t*)(ws + WS_META + 12288),
      (uint32_t*)(ws + WS_SORTED));

  k3_lstm_fused<<<256, 512, 0, stream>>>(x, done, h0, c0,
      (const short*)(ws + WS_WMAIN), (const float*)(ws + WS_BMAIN),
      (const short*)(ws + WS_WA1P), (const short*)(ws + WS_WV1P),
      (const short*)(ws + WS_WA2P), (const short*)(ws + WS_WV2P),
      ba1, bv1, ba2, bv2, wa3, ba3, wv3, bv3,
      mask, (const uint32_t*)(ws + WS_META + 16),
      (const uint32_t*)(ws + WS_SORTED), (const uint32_t*)(ws + WS_META),
      outLogits, outValue, outHn, outCn);

  (void)in_sizes; (void)n_in; (void)out_size; (void)ws_size;
}

// Round 5
// 5795.274 us; speedup vs baseline: 1.8901x; 1.0608x over previous
//
#include <hip/hip_runtime.h>
#include <hip/hip_bf16.h>
#include <stdint.h>
#include <stddef.h>

// ============================================================================
// PPOAgent fused pipeline for MI355X (gfx950) — v5
// LSTM(1024,BS=512,IN=128,H=256) + 2 MLP heads.
// v5 vs v4:
//  - k2b/k2d: LDS-histogram versions (atomics 524K -> ~8K)  [~3 ms saved]
//  - k3 split: recurrence-only kernel (128 segs/block, 1024 thr, 16 waves,
//    2 barriers/iter, no spill target), writes hidden bf16 to ws
//  - k4: dense fused-heads GEMM kernel over all 524288 hidden rows
//  - host gate on ws_size; fallback = v4 fused kernel (proven correct)
// ============================================================================

typedef short bf16x8 __attribute__((ext_vector_type(8)));
typedef short bf16x4 __attribute__((ext_vector_type(4)));
typedef float f32x4  __attribute__((ext_vector_type(4)));

#define LOG2E 1.44269504088896340736f

__device__ __forceinline__ float fexp2(float x){ return __builtin_amdgcn_exp2f(x); }
__device__ __forceinline__ float frcpf_(float x){ return __builtin_amdgcn_rcpf(x); }
__device__ __forceinline__ float fsig(float x){ return frcpf_(1.0f + fexp2(-x*LOG2E)); }
__device__ __forceinline__ float ftanh_(float x){ return 1.0f - 2.0f*frcpf_(1.0f + fexp2(x*(2.0f*LOG2E))); }

__device__ __forceinline__ short f2bf(float f){
  unsigned u = __builtin_bit_cast(unsigned, f);
  u += 0x7fffu + ((u>>16)&1u);
  return (short)(u>>16);
}
__device__ __forceinline__ float bf2f(short h){
  unsigned u = ((unsigned)(unsigned short)h)<<16;
  return __builtin_bit_cast(float, u);
}

// ---------------- workspace layout (bytes) ----------------
static constexpr size_t WS_WMAIN  = 0;          // packed [Wih;Whh] A-frag stream, 384x1024 bf16
static constexpr size_t WS_WA1P   = 786432;
static constexpr size_t WS_WV1P   = 851968;
static constexpr size_t WS_WA2P   = 917504;
static constexpr size_t WS_WV2P   = 950272;
static constexpr size_t WS_BMAIN  = 983040;     // 1024 f32 packed-order bias
static constexpr size_t WS_META   = 1048576;    // nSegs@+0 ; maskMode@+16 ; hist@+4096 ; curs@+12288
static constexpr size_t WS_SEGS   = 1081344;    // 524288 u32
static constexpr size_t WS_SORTED = 3178496;    // 524288 u32  (end 5275648)
static constexpr size_t WS_HID    = 5275648;    // 524288 x 256 bf16 = 268435456
static constexpr size_t WS_NEED_SPLIT = WS_HID + 268435456; // 273711104

// ============================================================================
// K0a: pack [W_ih; W_hh] as MFMA A-fragment stream + packed-order bias.
// cgp = gq*256 + nt*16 + u*4 + e : j = gq*64+u*16+nt, gate e, g = e*256+j.
// Chunk (kt,gq): addr(short) = (kt*4+gq)*8192 + nt*512 + lane*8
// ============================================================================
__global__ void k0a_packmain(const float* __restrict__ wih, const float* __restrict__ whh,
                             const float* __restrict__ bih, const float* __restrict__ bhh,
                             short* __restrict__ wp, float* __restrict__ bp)
{
  int tidg = blockIdx.x*512 + threadIdx.x;     // 0..49151
  {
    int lane = tidg & 63;
    int nt   = (tidg>>6) & 15;
    int ci   = tidg>>10;                       // 0..47
    int kt = ci>>2, gq = ci&3;
    int gs = lane & 15;
    int ug = gs>>2, eg = gs&3;
    int j  = gq*64 + ug*16 + nt;
    int g  = eg*256 + j;
    int k0 = kt*32 + (lane>>4)*8;
    bf16x8 ov;
#pragma unroll
    for (int jj=0;jj<8;++jj){
      int k = k0 + jj;
      float v = (k < 128) ? wih[(size_t)g*128 + k] : whh[(size_t)g*256 + (k-128)];
      ov[jj] = f2bf(v);
    }
    *(bf16x8*)(wp + (size_t)tidg*8) = ov;
  }
  if (tidg < 1024) {
    int cgp = tidg;
    int gq = cgp>>8, nt = (cgp>>4)&15, ug = (cgp>>2)&3, eg = cgp&3;
    int g = eg*256 + gq*64 + ug*16 + nt;
    bp[cgp] = bih[g] + bhh[g];
  }
}

// K0b: pack head weights (N x K row-major -> frag stream)
__global__ void k0b_packheads(const float* __restrict__ wa1, const float* __restrict__ wv1,
                              const float* __restrict__ wa2, const float* __restrict__ wv2,
                              short* __restrict__ wa1p, short* __restrict__ wv1p,
                              short* __restrict__ wa2p, short* __restrict__ wv2p)
{
  int p = blockIdx.x*512 + threadIdx.x;     // 0..12287
  const float* src; short* dst; int K; int pl;
  if (p < 4096)       { src=wa1; dst=wa1p; K=256; pl=p; }
  else if (p < 8192)  { src=wv1; dst=wv1p; K=256; pl=p-4096; }
  else if (p < 10240) { src=wa2; dst=wa2p; K=128; pl=p-8192; }
  else                { src=wv2; dst=wv2p; K=128; pl=p-10240; }
  int lane = pl & 63;
  int f    = pl >> 6;
  int nt   = f & 7;
  int kt   = f >> 3;
  int n  = nt*16 + (lane&15);
  int k0 = kt*32 + (lane>>4)*8;
  bf16x8 ov;
#pragma unroll
  for (int j=0;j<8;++j) ov[j] = f2bf(src[(size_t)n*K + k0 + j]);
  *(bf16x8*)(dst + (size_t)pl*8) = ov;
}

// K1: detect mask storage layout (byte-bools vs int32).
__global__ void k1_maskmode(const unsigned char* __restrict__ mask, uint32_t* __restrict__ flag)
{
  int i = blockIdx.x*256 + threadIdx.x;
  uint32_t v = ((i & 3) != 0) ? (uint32_t)mask[i] : 0u;
  if (v) atomicOr((unsigned int*)flag, 1u);
}

// ============================================================================
// K2a: per batch column, find segment starts. record = (len-1)<<19|start<<9|b
// ============================================================================
__global__ void k2a_segments(const int* __restrict__ done, uint32_t* __restrict__ segs,
                             uint32_t* __restrict__ nSegs)
{
  const int b = blockIdx.x;
  const int tid = threadIdx.x;
  __shared__ uint16_t starts[1025];
  __shared__ uint32_t cnts[256];
  __shared__ uint32_t basePos;

  uint32_t my[4]; int myn = 0;
  int t0 = tid*4;
#pragma unroll
  for (int i=0;i<4;++i){
    int t = t0 + i;
    int d = done[(size_t)t*512 + b];
    if (t == 0 || d != 0) my[myn++] = (uint32_t)t;
  }
  cnts[tid] = (uint32_t)myn;
  __syncthreads();
  for (int off=1; off<256; off<<=1){
    uint32_t v = (tid >= off) ? cnts[tid-off] : 0u;
    __syncthreads();
    cnts[tid] += v;
    __syncthreads();
  }
  uint32_t myBase = cnts[tid] - (uint32_t)myn;
  uint32_t ns = cnts[255];
  for (int i=0;i<myn;++i) starts[myBase+i] = (uint16_t)my[i];
  if (tid == 0) {
    starts[ns] = 1024;
    basePos = atomicAdd((unsigned int*)nSegs, ns);
  }
  __syncthreads();
  for (uint32_t i = tid; i < ns; i += 256) {
    uint32_t st = starts[i];
    uint32_t ln = (uint32_t)starts[i+1] - st;
    segs[basePos + i] = ((ln-1u)<<19) | (st<<9) | (uint32_t)b;
  }
}

// K2b v5: LDS histogram, ~30 global atomics per block.
__global__ void k2b_hist(const uint32_t* __restrict__ segs, const uint32_t* __restrict__ nSegs,
                         uint32_t* __restrict__ hist)
{
  __shared__ uint32_t lh[1025];
  const uint32_t n = *nSegs;
  for (int i = threadIdx.x; i < 1025; i += 512) lh[i] = 0;
  __syncthreads();
  for (uint32_t i = blockIdx.x*512u + threadIdx.x; i < n; i += gridDim.x*512u) {
    uint32_t ln = ((segs[i]>>19)&1023u) + 1u;
    atomicAdd(&lh[ln], 1u);
  }
  __syncthreads();
  for (int i = threadIdx.x; i < 1025; i += 512)
    if (lh[i]) atomicAdd((unsigned int*)&hist[i], lh[i]);
}

// K2c: bucketStart[len] = #segments with length > len (descending sort)
__global__ void k2c_scan(const uint32_t* __restrict__ hist, uint32_t* __restrict__ curs)
{
  __shared__ uint32_t s[1024];
  const int tid = threadIdx.x;
  uint32_t own = hist[tid+1];
  s[tid] = own;
  __syncthreads();
  for (int off=1; off<1024; off<<=1){
    uint32_t v = (tid+off < 1024) ? s[tid+off] : 0u;
    __syncthreads();
    s[tid] += v;
    __syncthreads();
  }
  curs[tid+1] = s[tid] - own;
  if (tid == 0) curs[0] = 0;
}

// K2d v5: per-block count -> one global atomic per (block,bin) -> local place.
__global__ void k2d_scatter(const uint32_t* __restrict__ segs, const uint32_t* __restrict__ nSegs,
                            uint32_t* __restrict__ curs, uint32_t* __restrict__ sorted)
{
  __shared__ uint32_t lh[1025];
  __shared__ uint32_t base[1025];
  const uint32_t n = *nSegs;
  const uint32_t chunk = (n + 127u) >> 7;          // gridDim.x == 128
  const uint32_t lo = blockIdx.x * chunk;
  const uint32_t hi = (lo + chunk < n) ? (lo + chunk) : n;
  for (int i = threadIdx.x; i < 1025; i += 512) lh[i] = 0;
  __syncthreads();
  for (uint32_t i = lo + threadIdx.x; i < hi; i += 512u) {
    uint32_t ln = ((segs[i]>>19)&1023u) + 1u;
    atomicAdd(&lh[ln], 1u);
  }
  __syncthreads();
  for (int i = threadIdx.x; i < 1025; i += 512) {
    uint32_t c = lh[i];
    if (c) base[i] = atomicAdd((unsigned int*)&curs[i], c);
    lh[i] = 0;
  }
  __syncthreads();
  for (uint32_t i = lo + threadIdx.x; i < hi; i += 512u) {
    uint32_t r = segs[i];
    uint32_t ln = ((r>>19)&1023u) + 1u;
    uint32_t pos = base[ln] + atomicAdd(&lh[ln], 1u);
    sorted[pos] = r;
  }
}

// ============================================================================
// K3r v5 (split path): recurrence only. 1024 thr = 16 waves = (gq 0..3)x(rq 0..3).
// Wave: gates gq*256..+256 x rows rq*32..+32 (rA=rq*32+cl, rB=rA+16), acc 2x16.
// A-tile [128][768B] swz ^(row&7)<<4. 2 barriers/iter. hidden store at loop top.
// ============================================================================
__global__ __launch_bounds__(1024, 4) void k3r_lstm(
    const float* __restrict__ x, const int* __restrict__ done,
    const float* __restrict__ h0, const float* __restrict__ c0,
    const short* __restrict__ wpack, const float* __restrict__ bpack,
    const uint32_t* __restrict__ sortedSegs, const uint32_t* __restrict__ nSegsPtr,
    short* __restrict__ hidden, float* __restrict__ hnOut, float* __restrict__ cnOut)
{
  __shared__ char smem[103936];
  char* Alds = smem;                            // [128][768] swizzled
  float* biasL = (float*)(smem + 98304);        // 1024 f32
  uint32_t* meta = (uint32_t*)(smem + 102400);  // b[128], st@+128, len@+256

  const int tid  = threadIdx.x;
  const int lane = tid & 63;
  const int wv   = tid >> 6;        // 0..15
  const int gq   = wv & 3;
  const int rq   = wv >> 2;
  const int cl   = lane & 15;
  const int u    = lane >> 4;
  const int ku   = u*16;
  const int swc  = (cl & 7) << 4;
  const int rA   = rq*32 + cl;
  const int rB   = rA + 16;
  const int jb   = gq*64 + u*16;
  const int jb2  = 2*jb;

  const int row8 = tid >> 3;        // 0..127
  const int oct  = tid & 7;
  const int rsw8 = (row8 & 7) << 4;

  biasL[tid] = bpack[tid];

  const uint32_t nSegs = *nSegsPtr;
  const uint32_t nGroups = (nSegs + 127u) >> 7;

  for (uint32_t g = blockIdx.x; g < nGroups; g += gridDim.x) {
    __syncthreads();                       // prev group fully consumed
    if (tid < 128) {
      uint32_t idx = g*128u + (uint32_t)tid;
      uint32_t b=0, st=0, ln=0;
      if (idx < nSegs) {
        uint32_t r = sortedSegs[idx];
        b = r & 511u; st = (r>>9)&1023u; ln = ((r>>19)&1023u) + 1u;
      }
      meta[tid] = b; meta[128+tid] = st; meta[256+tid] = ln;
    }
    __syncthreads();

    const uint32_t mb8  = meta[row8];
    const uint32_t mst8 = meta[128+row8];
    const uint32_t mln8 = meta[256+row8];
    const uint32_t mbA  = meta[rA],     mbB  = meta[rB];
    const uint32_t mstA = meta[128+rA], mstB = meta[128+rB];
    const uint32_t mlnA = meta[256+rA], mlnB = meta[256+rB];
    const int maxLen = (int)meta[256];   // desc sort

    // ---- group init: x(iter0) [0,256) + FULL h [256,768) ----
    {
      const bool act = (mln8 > 0u);
      float xf[16];
      if (act) {
        const float4* xp = (const float4*)(x + ((size_t)mst8*512u + mb8)*128u + (size_t)oct*16u);
#pragma unroll
        for (int i=0;i<4;++i){ float4 t4 = xp[i]; xf[4*i]=t4.x; xf[4*i+1]=t4.y; xf[4*i+2]=t4.z; xf[4*i+3]=t4.w; }
      } else {
#pragma unroll
        for (int i=0;i<16;++i) xf[i]=0.0f;
      }
      bf16x8 v0, v1;
#pragma unroll
      for (int j=0;j<8;++j){ v0[j]=f2bf(xf[j]); v1[j]=f2bf(xf[8+j]); }
      *(bf16x8*)(Alds + row8*768 + ((oct*32     ) ^ rsw8)) = v0;
      *(bf16x8*)(Alds + row8*768 + ((oct*32 + 16) ^ rsw8)) = v1;

      const bool useInit = act && (mst8 == 0u) && (done[mb8] == 0);
      float hf[32];
      if (useInit) {
        const float4* hp = (const float4*)(h0 + (size_t)mb8*256u + (size_t)oct*32u);
#pragma unroll
        for (int i=0;i<8;++i){ float4 t4 = hp[i]; hf[4*i]=t4.x; hf[4*i+1]=t4.y; hf[4*i+2]=t4.z; hf[4*i+3]=t4.w; }
      } else {
#pragma unroll
        for (int i=0;i<32;++i) hf[i]=0.0f;
      }
#pragma unroll
      for (int q=0;q<4;++q){
        bf16x8 hv;
#pragma unroll
        for (int j=0;j<8;++j) hv[j]=f2bf(hf[q*8+j]);
        *(bf16x8*)(Alds + row8*768 + ((256 + oct*64 + q*16) ^ rsw8)) = hv;
      }
    }

    // ---- c state init ----
    float cregA[16], cregB[16];
    {
      const bool initA = (mlnA > 0u) && (mstA == 0u) && (done[mbA] == 0);
      const bool initB = (mlnB > 0u) && (mstB == 0u) && (done[mbB] == 0);
      f32x4 ca[4], cb[4];
#pragma unroll
      for (int q=0;q<4;++q){
        ca[q] = initA ? *(const f32x4*)(c0 + (size_t)mbA*256u + jb + q*4) : (f32x4){0.f,0.f,0.f,0.f};
        cb[q] = initB ? *(const f32x4*)(c0 + (size_t)mbB*256u + jb + q*4) : (f32x4){0.f,0.f,0.f,0.f};
      }
#pragma unroll
      for (int nt=0;nt<16;++nt){ cregA[nt]=ca[nt>>2][nt&3]; cregB[nt]=cb[nt>>2][nt&3]; }
    }

    for (int it = 0; it < maxLen; ++it) {
      __syncthreads();                   // S1: A-tile (x_t, h_{t-1}) ready

      // ---- store hidden h_{t-1} (read-only vs concurrent GEMM reads) ----
      if (it >= 1 && (uint32_t)(it-1) < mln8) {
        const size_t grow = (size_t)(mst8 + (uint32_t)(it-1))*512u + mb8;
        short* hp = hidden + grow*256u + (size_t)oct*32u;
#pragma unroll
        for (int q=0;q<4;++q)
          *(bf16x8*)(hp + q*8) = *(const bf16x8*)(Alds + row8*768 + ((256 + oct*64 + q*16) ^ rsw8));
      }

      // ---- GEMM: C[gates][rows] = Wp @ [x|h]^T + bias ----
      f32x4 accA[16], accB[16];
#pragma unroll
      for (int nt=0;nt<16;++nt){
        f32x4 bv = *(const f32x4*)(biasL + gq*256 + nt*16 + u*4);
        accA[nt]=bv; accB[nt]=bv;
      }
      for (int kt=0; kt<12; ++kt) {
        const short* wkt = wpack + (size_t)(kt*4 + gq)*8192 + lane*8;
        bf16x8 bfA = *(const bf16x8*)(Alds + rA*768 + ((kt*64 + ku) ^ swc));
        bf16x8 bfB = *(const bf16x8*)(Alds + rB*768 + ((kt*64 + ku) ^ swc));
#pragma unroll
        for (int nt=0;nt<16;++nt) {
          const bf16x8 wf = *(const bf16x8*)(wkt + nt*512);
          accA[nt] = __builtin_amdgcn_mfma_f32_16x16x32_bf16(wf, bfA, accA[nt], 0,0,0);
          accB[nt] = __builtin_amdgcn_mfma_f32_16x16x32_bf16(wf, bfB, accB[nt], 0,0,0);
        }
      }

      // ---- x prefetch for it+1 ----
      float4 xq0,xq1,xq2,xq3;
      {
        const bool xact = (it + 1) < (int)mln8;
        if (xact) {
          const float4* xp = (const float4*)(x + ((size_t)(mst8+it+1u)*512u + mb8)*128u + (size_t)oct*16u);
          xq0=xp[0]; xq1=xp[1]; xq2=xp[2]; xq3=xp[3];
        } else {
          xq0=xq1=xq2=xq3=make_float4(0.f,0.f,0.f,0.f);
        }
      }

      __syncthreads();                   // S2: GEMM reads done; A writable

      // ---- LSTM cell (per-lane regs) ----
      float hfA[16], hfB[16];
#pragma unroll
      for (int nt=0;nt<16;++nt) {
        f32x4 gA = accA[nt];
        float i0=fsig(gA[0]), f0=fsig(gA[1]), g0=ftanh_(gA[2]), o0=fsig(gA[3]);
        float cA = f0*cregA[nt] + i0*g0; cregA[nt]=cA; hfA[nt] = o0*ftanh_(cA);
        f32x4 gB = accB[nt];
        float i1=fsig(gB[0]), f1=fsig(gB[1]), g1=ftanh_(gB[2]), o1=fsig(gB[3]);
        float cB = f1*cregB[nt] + i1*g1; cregB[nt]=cB; hfB[nt] = o1*ftanh_(cB);
      }
      const bool cactA = it < (int)mlnA;
      const bool cactB = it < (int)mlnB;
      if (cactA) {
        bf16x8 hv0, hv1;
#pragma unroll
        for (int q=0;q<8;++q){ hv0[q]=f2bf(hfA[q]); hv1[q]=f2bf(hfA[8+q]); }
        *(bf16x8*)(Alds + rA*768 + ((256 + jb2     ) ^ swc)) = hv0;
        *(bf16x8*)(Alds + rA*768 + ((256 + jb2 + 16) ^ swc)) = hv1;
      }
      if (cactB) {
        bf16x8 hv0, hv1;
#pragma unroll
        for (int q=0;q<8;++q){ hv0[q]=f2bf(hfB[q]); hv1[q]=f2bf(hfB[8+q]); }
        *(bf16x8*)(Alds + rB*768 + ((256 + jb2     ) ^ swc)) = hv0;
        *(bf16x8*)(Alds + rB*768 + ((256 + jb2 + 16) ^ swc)) = hv1;
      }
      if (cactA && (it == (int)mlnA - 1) && (mstA + mlnA == 1024u)) {
        float4* hp4 = (float4*)(hnOut + (size_t)mbA*256u + jb);
        float4* cp4 = (float4*)(cnOut + (size_t)mbA*256u + jb);
#pragma unroll
        for (int q=0;q<4;++q){
          hp4[q] = make_float4(hfA[4*q],hfA[4*q+1],hfA[4*q+2],hfA[4*q+3]);
          cp4[q] = make_float4(cregA[4*q],cregA[4*q+1],cregA[4*q+2],cregA[4*q+3]);
        }
      }
      if (cactB && (it == (int)mlnB - 1) && (mstB + mlnB == 1024u)) {
        float4* hp4 = (float4*)(hnOut + (size_t)mbB*256u + jb);
        float4* cp4 = (float4*)(cnOut + (size_t)mbB*256u + jb);
#pragma unroll
        for (int q=0;q<4;++q){
          hp4[q] = make_float4(hfB[4*q],hfB[4*q+1],hfB[4*q+2],hfB[4*q+3]);
          cp4[q] = make_float4(cregB[4*q],cregB[4*q+1],cregB[4*q+2],cregB[4*q+3]);
        }
      }
      // next-step x into A-tile
      {
        float xf[16];
        xf[0]=xq0.x; xf[1]=xq0.y; xf[2]=xq0.z; xf[3]=xq0.w;
        xf[4]=xq1.x; xf[5]=xq1.y; xf[6]=xq1.z; xf[7]=xq1.w;
        xf[8]=xq2.x; xf[9]=xq2.y; xf[10]=xq2.z; xf[11]=xq2.w;
        xf[12]=xq3.x; xf[13]=xq3.y; xf[14]=xq3.z; xf[15]=xq3.w;
        bf16x8 v0, v1;
#pragma unroll
        for (int j=0;j<8;++j){ v0[j]=f2bf(xf[j]); v1[j]=f2bf(xf[8+j]); }
        *(bf16x8*)(Alds + row8*768 + ((oct*32     ) ^ rsw8)) = v0;
        *(bf16x8*)(Alds + row8*768 + ((oct*32 + 16) ^ rsw8)) = v1;
      }
    }

    // ---- final hidden store for rows whose segment ran to maxLen ----
    __syncthreads();
    if (maxLen > 0 && mln8 == (uint32_t)maxLen) {
      const size_t grow = (size_t)(mst8 + (uint32_t)(maxLen-1))*512u + mb8;
      short* hp = hidden + grow*256u + (size_t)oct*32u;
#pragma unroll
      for (int q=0;q<4;++q)
        *(bf16x8*)(hp + q*8) = *(const bf16x8*)(Alds + row8*768 + ((256 + oct*64 + q*16) ^ rsw8));
    }
  }
}

// ============================================================================
// K4 v5 (split path): fused heads over dense hidden rows. 512 thr = 8 waves
// = (gq 0..3)x(rh 0..1); heads sequential (hd loop). 64 rows/block.
// ============================================================================
__global__ __launch_bounds__(512, 2) void k4_heads(
    const short* __restrict__ hidden,
    const short* __restrict__ wa1p, const short* __restrict__ wv1p,
    const short* __restrict__ wa2p, const short* __restrict__ wv2p,
    const float* __restrict__ ba1, const float* __restrict__ bv1,
    const float* __restrict__ ba2, const float* __restrict__ bv2,
    const float* __restrict__ wa3, const float* __restrict__ ba3,
    const float* __restrict__ wv3, const float* __restrict__ bv3,
    const unsigned char* __restrict__ maskB, const uint32_t* __restrict__ maskModePtr,
    float* __restrict__ logits, float* __restrict__ value)
{
  __shared__ char smem[67600];
  char* hidL = smem;                      // [64][512] swizzled
  char* hb1  = smem + 32768;              // [64][256]
  char* hb2  = smem + 49152;              // [64][256]
  float* w3L = (float*)(smem + 65536);    // [4][128]
  float* b3L = (float*)(smem + 67584);

  const int tid  = threadIdx.x;
  const int lane = tid & 63;
  const int wv   = tid >> 6;       // 0..7
  const int gq   = wv & 3;
  const int rh   = wv >> 2;
  const int cl   = lane & 15;
  const int u    = lane >> 4;
  const int ku   = u*16;
  const int swc  = (cl & 7) << 4;
  const int row8 = tid >> 3;       // 0..63
  const int oct  = tid & 7;
  const int rsw8 = (row8 & 7) << 4;
  const size_t r0 = (size_t)blockIdx.x * 64u;

  // stage hidden rows -> LDS (inverse of k3r's store layout)
  {
    const short* hp = hidden + (r0 + (size_t)row8)*256u + (size_t)oct*32u;
#pragma unroll
    for (int q=0;q<4;++q)
      *(bf16x8*)(hidL + row8*512 + ((oct*64 + q*16) ^ rsw8)) = *(const bf16x8*)(hp + q*8);
  }
  if (tid < 128) {
    w3L[tid]       = wa3[tid];
    w3L[128 + tid] = wa3[128 + tid];
    w3L[256 + tid] = wa3[256 + tid];
    w3L[384 + tid] = wv3[tid];
  }
  if (tid == 0) { b3L[0]=ba3[0]; b3L[1]=ba3[1]; b3L[2]=ba3[2]; b3L[3]=bv3[0]; }
  const uint32_t maskByteMode = *maskModePtr;
  const int* maskI = (const int*)maskB;
  __syncthreads();

  for (int hd = 0; hd < 2; ++hd) {
    const short* w1p = hd ? wv1p : wa1p;
    const short* w2p = hd ? wv2p : wa2p;
    const float* b1  = hd ? bv1 : ba1;
    const float* b2  = hd ? bv2 : ba2;

    // L1 (K=256): rows rh*32 + r4*16 + cl, n-slice gq*32 + n1*16 + u*4
    {
      f32x4 h1[2][2];
#pragma unroll
      for (int n1=0;n1<2;++n1){
        f32x4 bv = *(const f32x4*)(b1 + gq*32 + n1*16 + u*4);
        h1[n1][0]=bv; h1[n1][1]=bv;
      }
      for (int kt2=0; kt2<8; ++kt2) {
        bf16x8 bh[2];
#pragma unroll
        for (int r4=0;r4<2;++r4)
          bh[r4] = *(const bf16x8*)(hidL + (rh*32 + r4*16 + cl)*512 + ((kt2*64 + ku) ^ swc));
#pragma unroll
        for (int n1=0;n1<2;++n1) {
          const bf16x8 wf = *(const bf16x8*)(w1p + (size_t)(kt2*8 + gq*2 + n1)*512 + lane*8);
#pragma unroll
          for (int r4=0;r4<2;++r4)
            h1[n1][r4] = __builtin_amdgcn_mfma_f32_16x16x32_bf16(wf, bh[r4], h1[n1][r4], 0,0,0);
        }
      }
#pragma unroll
      for (int n1=0;n1<2;++n1){
#pragma unroll
        for (int r4=0;r4<2;++r4){
          bf16x4 hv;
#pragma unroll
          for (int e=0;e<4;++e) hv[e] = f2bf(ftanh_(h1[n1][r4][e]));
          int row = rh*32 + r4*16 + cl;
          *(bf16x4*)(hb1 + row*256 + ((2*(gq*32 + n1*16 + u*4)) ^ swc)) = hv;
        }
      }
    }
    __syncthreads();                 // hb1 ready

    // L2 (K=128)
    {
      f32x4 h2[2][2];
#pragma unroll
      for (int n1=0;n1<2;++n1){
        f32x4 bv = *(const f32x4*)(b2 + gq*32 + n1*16 + u*4);
        h2[n1][0]=bv; h2[n1][1]=bv;
      }
      for (int kt2=0; kt2<4; ++kt2) {
        bf16x8 bh[2];
#pragma unroll
        for (int r4=0;r4<2;++r4)
          bh[r4] = *(const bf16x8*)(hb1 + (rh*32 + r4*16 + cl)*256 + ((kt2*64 + ku) ^ swc));
#pragma unroll
        for (int n1=0;n1<2;++n1) {
          const bf16x8 wf = *(const bf16x8*)(w2p + (size_t)(kt2*8 + gq*2 + n1)*512 + lane*8);
#pragma unroll
          for (int r4=0;r4<2;++r4)
            h2[n1][r4] = __builtin_amdgcn_mfma_f32_16x16x32_bf16(wf, bh[r4], h2[n1][r4], 0,0,0);
        }
      }
#pragma unroll
      for (int n1=0;n1<2;++n1){
#pragma unroll
        for (int r4=0;r4<2;++r4){
          bf16x4 hv;
#pragma unroll
          for (int e=0;e<4;++e) hv[e] = f2bf(ftanh_(h2[n1][r4][e]));
          int row = rh*32 + r4*16 + cl;
          *(bf16x4*)(hb2 + row*256 + ((2*(gq*32 + n1*16 + u*4)) ^ swc)) = hv;
        }
      }
    }
    __syncthreads();                 // hb2 ready

    // final layer for this head
    {
      const int row  = tid >> 3;
      const int o    = (tid >> 1) & 3;
      const int half = tid & 1;
      const int sw   = (row&7)<<4;
      float s = half ? 0.0f : b3L[o];
      const float* wr = w3L + o*128 + half*64;
#pragma unroll
      for (int k16=0; k16<8; ++k16) {
        bf16x8 av = *(const bf16x8*)(hb2 + row*256 + (((half*8 + k16)*16) ^ sw));
#pragma unroll
        for (int j=0;j<8;++j) s += bf2f(av[j]) * wr[k16*8+j];
      }
      s += __shfl_xor(s, 1);
      if (half == 0) {
        const size_t grow = r0 + (size_t)row;
        if (hd == 0 && o < 3) {
          const size_t mi = grow*3u + (size_t)o;
          const bool masked = maskByteMode ? (maskB[mi] != 0) : (maskI[mi] != 0);
          logits[mi] = masked ? -1e8f : s;
        } else if (hd == 1 && o == 3) {
          value[grow] = s;
        }
      }
    }
    __syncthreads();                 // hb2/hb1 free for next head
  }
}

// ============================================================================
// K3 fused fallback (v4, proven): used when ws_size too small for hidden.
// ============================================================================
__global__ __launch_bounds__(512, 2) void k3_lstm_fused(
    const float* __restrict__ x, const int* __restrict__ done,
    const float* __restrict__ h0, const float* __restrict__ c0,
    const short* __restrict__ wpack, const float* __restrict__ bpack,
    const short* __restrict__ wa1p, const short* __restrict__ wv1p,
    const short* __restrict__ wa2p, const short* __restrict__ wv2p,
    const float* __restrict__ ba1, const float* __restrict__ bv1,
    const float* __restrict__ ba2, const float* __restrict__ bv2,
    const float* __restrict__ wa3, const float* __restrict__ ba3,
    const float* __restrict__ wv3, const float* __restrict__ bv3,
    const unsigned char* __restrict__ maskB,
    const uint32_t* __restrict__ maskModePtr,
    const uint32_t* __restrict__ sortedSegs, const uint32_t* __restrict__ nSegsPtr,
    float* __restrict__ logits, float* __restrict__ value,
    float* __restrict__ hnOut, float* __restrict__ cnOut)
{
  __shared__ char smem[121616];
  char* Alds = smem;
  char* hb1  = smem + 49152;
  char* hb2  = smem + 81920;
  float* biasL = (float*)(smem + 114688);
  uint32_t* meta = (uint32_t*)(smem + 118784);
  float* w3L = (float*)(smem + 119552);
  float* b3L = (float*)(smem + 121600);

  const int tid  = threadIdx.x;
  const int lane = tid & 63;
  const int wv   = tid >> 6;
  const int gq   = wv & 3;
  const int hd   = wv >> 2;
  const int cl   = lane & 15;
  const int u    = lane >> 4;
  const int ku   = u*16;
  const int swc  = (cl & 7) << 4;
  const int rA   = hd*32 + cl;
  const int rB   = rA + 16;
  const int jb   = gq*64 + u*16;
  const int jb2  = 2*jb;

  const int row8 = tid >> 3;
  const int oct  = tid & 7;
  const int rsw8 = (row8 & 7) << 4;

  biasL[tid]       = bpack[tid];
  biasL[512 + tid] = bpack[512 + tid];
  if (tid < 128) {
    w3L[tid]       = wa3[tid];
    w3L[128 + tid] = wa3[128 + tid];
    w3L[256 + tid] = wa3[256 + tid];
    w3L[384 + tid] = wv3[tid];
  }
  if (tid == 0) { b3L[0]=ba3[0]; b3L[1]=ba3[1]; b3L[2]=ba3[2]; b3L[3]=bv3[0]; }

  float4 bH1v[2], bH2v[2];
  {
    const float* b1 = hd ? bv1 : ba1;
    const float* b2 = hd ? bv2 : ba2;
#pragma unroll
    for (int n1=0; n1<2; ++n1) {
      bH1v[n1] = *(const float4*)(b1 + gq*32 + n1*16 + u*4);
      bH2v[n1] = *(const float4*)(b2 + gq*32 + n1*16 + u*4);
    }
  }
  const short* w1p = hd ? wv1p : wa1p;
  const short* w2p = hd ? wv2p : wa2p;

  const uint32_t maskByteMode = *maskModePtr;
  const int* maskI = (const int*)maskB;

  const uint32_t nSegs = *nSegsPtr;
  const uint32_t nGroups = (nSegs + 63u) >> 6;

  for (uint32_t g = blockIdx.x; g < nGroups; g += gridDim.x) {
    __syncthreads();
    if (tid < 64) {
      uint32_t idx = g*64u + (uint32_t)tid;
      uint32_t b=0, st=0, ln=0;
      if (idx < nSegs) {
        uint32_t r = sortedSegs[idx];
        b = r & 511u; st = (r>>9)&1023u; ln = ((r>>19)&1023u) + 1u;
      }
      meta[tid] = b; meta[64+tid] = st; meta[128+tid] = ln;
    }
    __syncthreads();

    const uint32_t mb8  = meta[row8];
    const uint32_t mst8 = meta[64+row8];
    const uint32_t mln8 = meta[128+row8];
    const uint32_t mbA  = meta[rA],    mbB  = meta[rB];
    const uint32_t mstA = meta[64+rA], mstB = meta[64+rB];
    const uint32_t mlnA = meta[128+rA],mlnB = meta[128+rB];
    const int maxLen = (int)meta[128];

    {
      const bool act = (mln8 > 0u);
      float xf[16];
      if (act) {
        const float4* xp = (const float4*)(x + ((size_t)mst8*512u + mb8)*128u + (size_t)oct*16u);
#pragma unroll
        for (int i=0;i<4;++i){ float4 t4 = xp[i]; xf[4*i]=t4.x; xf[4*i+1]=t4.y; xf[4*i+2]=t4.z; xf[4*i+3]=t4.w; }
      } else {
#pragma unroll
        for (int i=0;i<16;++i) xf[i]=0.0f;
      }
      bf16x8 v0, v1;
#pragma unroll
      for (int j=0;j<8;++j){ v0[j]=f2bf(xf[j]); v1[j]=f2bf(xf[8+j]); }
      *(bf16x8*)(Alds + row8*768 + ((oct*32     ) ^ rsw8)) = v0;
      *(bf16x8*)(Alds + row8*768 + ((oct*32 + 16) ^ rsw8)) = v1;

      const bool useInit = act && (mst8 == 0u) && (done[mb8] == 0);
      float hf[32];
      if (useInit) {
        const float4* hp = (const float4*)(h0 + (size_t)mb8*256u + (size_t)oct*32u);
#pragma unroll
        for (int i=0;i<8;++i){ float4 t4 = hp[i]; hf[4*i]=t4.x; hf[4*i+1]=t4.y; hf[4*i+2]=t4.z; hf[4*i+3]=t4.w; }
      } else {
#pragma unroll
        for (int i=0;i<32;++i) hf[i]=0.0f;
      }
#pragma unroll
      for (int q=0;q<4;++q){
        bf16x8 hv;
#pragma unroll
        for (int j=0;j<8;++j) hv[j]=f2bf(hf[q*8+j]);
        *(bf16x8*)(Alds + row8*768 + ((256 + oct*64 + q*16) ^ rsw8)) = hv;
      }
    }

    float cregA[16], cregB[16];
    {
      const bool initA = (mlnA > 0u) && (mstA == 0u) && (done[mbA] == 0);
      const bool initB = (mlnB > 0u) && (mstB == 0u) && (done[mbB] == 0);
      f32x4 ca[4], cb[4];
#pragma unroll
      for (int q=0;q<4;++q){
        ca[q] = initA ? *(const f32x4*)(c0 + (size_t)mbA*256u + jb + q*4) : (f32x4){0.f,0.f,0.f,0.f};
        cb[q] = initB ? *(const f32x4*)(c0 + (size_t)mbB*256u + jb + q*4) : (f32x4){0.f,0.f,0.f,0.f};
      }
#pragma unroll
      for (int nt=0;nt<16;++nt){ cregA[nt]=ca[nt>>2][nt&3]; cregB[nt]=cb[nt>>2][nt&3]; }
    }

    for (int it = 0; it < maxLen; ++it) {
      __syncthreads();

      f32x4 accA[16], accB[16];
#pragma unroll
      for (int nt=0;nt<16;++nt){
        f32x4 bv = *(const f32x4*)(biasL + gq*256 + nt*16 + u*4);
        accA[nt]=bv; accB[nt]=bv;
      }
      for (int kt=0; kt<12; ++kt) {
        if ((kt & 3) == 0) __builtin_amdgcn_s_barrier();
        const short* wkt = wpack + (size_t)(kt*4 + gq)*8192 + lane*8;
        bf16x8 bfA = *(const bf16x8*)(Alds + rA*768 + ((kt*64 + ku) ^ swc));
        bf16x8 bfB = *(const bf16x8*)(Alds + rB*768 + ((kt*64 + ku) ^ swc));
#pragma unroll
        for (int nt=0;nt<16;++nt) {
          const bf16x8 wf = *(const bf16x8*)(wkt + nt*512);
          accA[nt] = __builtin_amdgcn_mfma_f32_16x16x32_bf16(wf, bfA, accA[nt], 0,0,0);
          accB[nt] = __builtin_amdgcn_mfma_f32_16x16x32_bf16(wf, bfB, accB[nt], 0,0,0);
        }
      }

      float4 xq0,xq1,xq2,xq3;
      {
        const bool xact = (it + 1) < (int)mln8;
        if (xact) {
          const float4* xp = (const float4*)(x + ((size_t)(mst8+it+1u)*512u + mb8)*128u + (size_t)oct*16u);
          xq0=xp[0]; xq1=xp[1]; xq2=xp[2]; xq3=xp[3];
        } else {
          xq0=xq1=xq2=xq3=make_float4(0.f,0.f,0.f,0.f);
        }
      }

      __syncthreads();

      float hfA[16], hfB[16];
#pragma unroll
      for (int nt=0;nt<16;++nt) {
        f32x4 gA = accA[nt];
        float i0=fsig(gA[0]), f0=fsig(gA[1]), g0=ftanh_(gA[2]), o0=fsig(gA[3]);
        float cA = f0*cregA[nt] + i0*g0; cregA[nt]=cA; hfA[nt] = o0*ftanh_(cA);
        f32x4 gB = accB[nt];
        float i1=fsig(gB[0]), f1=fsig(gB[1]), g1=ftanh_(gB[2]), o1=fsig(gB[3]);
        float cB = f1*cregB[nt] + i1*g1; cregB[nt]=cB; hfB[nt] = o1*ftanh_(cB);
      }
      {
        bf16x8 hv0, hv1;
#pragma unroll
        for (int q=0;q<8;++q){ hv0[q]=f2bf(hfA[q]); hv1[q]=f2bf(hfA[8+q]); }
        *(bf16x8*)(Alds + rA*768 + ((256 + jb2     ) ^ swc)) = hv0;
        *(bf16x8*)(Alds + rA*768 + ((256 + jb2 + 16) ^ swc)) = hv1;
#pragma unroll
        for (int q=0;q<8;++q){ hv0[q]=f2bf(hfB[q]); hv1[q]=f2bf(hfB[8+q]); }
        *(bf16x8*)(Alds + rB*768 + ((256 + jb2     ) ^ swc)) = hv0;
        *(bf16x8*)(Alds + rB*768 + ((256 + jb2 + 16) ^ swc)) = hv1;
      }
      if ((it == (int)mlnA - 1) && (mstA + mlnA == 1024u)) {
        float4* hp4 = (float4*)(hnOut + (size_t)mbA*256u + jb);
        float4* cp4 = (float4*)(cnOut + (size_t)mbA*256u + jb);
#pragma unroll
        for (int q=0;q<4;++q){
          hp4[q] = make_float4(hfA[4*q],hfA[4*q+1],hfA[4*q+2],hfA[4*q+3]);
          cp4[q] = make_float4(cregA[4*q],cregA[4*q+1],cregA[4*q+2],cregA[4*q+3]);
        }
      }
      if ((it == (int)mlnB - 1) && (mstB + mlnB == 1024u)) {
        float4* hp4 = (float4*)(hnOut + (size_t)mbB*256u + jb);
        float4* cp4 = (float4*)(cnOut + (size_t)mbB*256u + jb);
#pragma unroll
        for (int q=0;q<4;++q){
          hp4[q] = make_float4(hfB[4*q],hfB[4*q+1],hfB[4*q+2],hfB[4*q+3]);
          cp4[q] = make_float4(cregB[4*q],cregB[4*q+1],cregB[4*q+2],cregB[4*q+3]);
        }
      }
      {
        float xf[16];
        xf[0]=xq0.x; xf[1]=xq0.y; xf[2]=xq0.z; xf[3]=xq0.w;
        xf[4]=xq1.x; xf[5]=xq1.y; xf[6]=xq1.z; xf[7]=xq1.w;
        xf[8]=xq2.x; xf[9]=xq2.y; xf[10]=xq2.z; xf[11]=xq2.w;
        xf[12]=xq3.x; xf[13]=xq3.y; xf[14]=xq3.z; xf[15]=xq3.w;
        bf16x8 v0, v1;
#pragma unroll
        for (int j=0;j<8;++j){ v0[j]=f2bf(xf[j]); v1[j]=f2bf(xf[8+j]); }
        *(bf16x8*)(Alds + row8*768 + ((oct*32     ) ^ rsw8)) = v0;
        *(bf16x8*)(Alds + row8*768 + ((oct*32 + 16) ^ rsw8)) = v1;
      }

      __syncthreads();

      {
        f32x4 h1[2][4];
#pragma unroll
        for (int n1=0;n1<2;++n1){
          f32x4 bv = {bH1v[n1].x, bH1v[n1].y, bH1v[n1].z, bH1v[n1].w};
#pragma unroll
          for (int r4=0;r4<4;++r4) h1[n1][r4] = bv;
        }
        for (int kt2=0; kt2<8; ++kt2) {
          bf16x8 bh[4];
#pragma unroll
          for (int r4=0;r4<4;++r4)
            bh[r4] = *(const bf16x8*)(Alds + (r4*16+cl)*768 + ((256 + kt2*64 + ku) ^ swc));
#pragma unroll
          for (int n1=0;n1<2;++n1) {
            const bf16x8 wf = *(const bf16x8*)(w1p + (size_t)(kt2*8 + gq*2 + n1)*512 + lane*8);
#pragma unroll
            for (int r4=0;r4<4;++r4)
              h1[n1][r4] = __builtin_amdgcn_mfma_f32_16x16x32_bf16(wf, bh[r4], h1[n1][r4], 0,0,0);
          }
        }
#pragma unroll
        for (int n1=0;n1<2;++n1){
#pragma unroll
          for (int r4=0;r4<4;++r4){
            bf16x4 hv;
#pragma unroll
            for (int e=0;e<4;++e) hv[e] = f2bf(ftanh_(h1[n1][r4][e]));
            int row = r4*16 + cl;
            *(bf16x4*)(hb1 + hd*16384 + row*256 + ((2*(gq*32 + n1*16 + u*4)) ^ swc)) = hv;
          }
        }
      }
      __syncthreads();

      {
        f32x4 h2[2][4];
#pragma unroll
        for (int n1=0;n1<2;++n1){
          f32x4 bv = {bH2v[n1].x, bH2v[n1].y, bH2v[n1].z, bH2v[n1].w};
#pragma unroll
          for (int r4=0;r4<4;++r4) h2[n1][r4] = bv;
        }
        const char* hbIn = hb1 + hd*16384;
        for (int kt2=0; kt2<4; ++kt2) {
          bf16x8 bh[4];
#pragma unroll
          for (int r4=0;r4<4;++r4)
            bh[r4] = *(const bf16x8*)(hbIn + (r4*16+cl)*256 + ((kt2*64 + ku) ^ swc));
#pragma unroll
          for (int n1=0;n1<2;++n1) {
            const bf16x8 wf = *(const bf16x8*)(w2p + (size_t)(kt2*8 + gq*2 + n1)*512 + lane*8);
#pragma unroll
            for (int r4=0;r4<4;++r4)
              h2[n1][r4] = __builtin_amdgcn_mfma_f32_16x16x32_bf16(wf, bh[r4], h2[n1][r4], 0,0,0);
          }
        }
#pragma unroll
        for (int n1=0;n1<2;++n1){
#pragma unroll
          for (int r4=0;r4<4;++r4){
            bf16x4 hv;
#pragma unroll
            for (int e=0;e<4;++e) hv[e] = f2bf(ftanh_(h2[n1][r4][e]));
            int row = r4*16 + cl;
            *(bf16x4*)(hb2 + hd*16384 + row*256 + ((2*(gq*32 + n1*16 + u*4)) ^ swc)) = hv;
          }
        }
      }
      __syncthreads();

      {
        const int frow = tid >> 3;
        const int o    = (tid >> 1) & 3;
        const int half = tid & 1;
        const uint32_t fmb  = meta[frow];
        const uint32_t fmst = meta[64+frow];
        const uint32_t fmln = meta[128+frow];
        const char* srcb = (o < 3) ? hb2 : (hb2 + 16384);
        const int sw = (frow&7)<<4;
        float s = half ? 0.0f : b3L[o];
        const float* wr = w3L + o*128 + half*64;
#pragma unroll
        for (int k16=0; k16<8; ++k16) {
          bf16x8 av = *(const bf16x8*)(srcb + frow*256 + (((half*8 + k16)*16) ^ sw));
#pragma unroll
          for (int j=0;j<8;++j) s += bf2f(av[j]) * wr[k16*8+j];
        }
        s += __shfl_xor(s, 1);
        if (half == 0 && it < (int)fmln) {
          const size_t grow = (size_t)((int)fmst + it)*512u + fmb;
          if (o < 3) {
            const size_t mi = grow*3u + (size_t)o;
            const bool masked = maskByteMode ? (maskB[mi] != 0) : (maskI[mi] != 0);
            logits[mi] = masked ? -1e8f : s;
          } else {
            value[grow] = s;
          }
        }
      }
    }
  }
}

// ============================================================================
extern "C" void kernel_launch(void* const* d_in, const int* in_sizes, int n_in,
                              void* d_out, int out_size, void* d_ws, size_t ws_size,
                              hipStream_t stream) {
  const float* x    = (const float*)d_in[0];
  const int*   done = (const int*)d_in[1];
  const unsigned char* mask = (const unsigned char*)d_in[2];
  const float* h0   = (const float*)d_in[3];
  const float* c0   = (const float*)d_in[4];
  const float* wih  = (const float*)d_in[5];
  const float* whh  = (const float*)d_in[6];
  const float* bih  = (const float*)d_in[7];
  const float* bhh  = (const float*)d_in[8];
  const float* wa1  = (const float*)d_in[9];
  const float* ba1  = (const float*)d_in[10];
  const float* wa2  = (const float*)d_in[11];
  const float* ba2  = (const float*)d_in[12];
  const float* wa3  = (const float*)d_in[13];
  const float* ba3  = (const float*)d_in[14];
  const float* wv1  = (const float*)d_in[15];
  const float* bv1  = (const float*)d_in[16];
  const float* wv2  = (const float*)d_in[17];
  const float* bv2  = (const float*)d_in[18];
  const float* wv3  = (const float*)d_in[19];
  const float* bv3  = (const float*)d_in[20];

  char* ws = (char*)d_ws;
  float* outLogits = (float*)d_out;                 // 524288*3
  float* outValue  = outLogits + 1572864;           // 524288
  float* outHn     = outValue  + 524288;            // 131072
  float* outCn     = outHn     + 131072;            // 131072

  hipMemsetAsync(ws + WS_META, 0, 16384, stream);

  k0a_packmain<<<96, 512, 0, stream>>>(wih, whh, bih, bhh,
      (short*)(ws + WS_WMAIN), (float*)(ws + WS_BMAIN));
  k0b_packheads<<<24, 512, 0, stream>>>(wa1, wv1, wa2, wv2,
      (short*)(ws + WS_WA1P), (short*)(ws + WS_WV1P),
      (short*)(ws + WS_WA2P), (short*)(ws + WS_WV2P));

  k1_maskmode<<<64, 256, 0, stream>>>(mask, (uint32_t*)(ws + WS_META + 16));

  k2a_segments<<<512, 256, 0, stream>>>(done, (uint32_t*)(ws + WS_SEGS),
                                        (uint32_t*)(ws + WS_META));
  k2b_hist<<<128, 512, 0, stream>>>((const uint32_t*)(ws + WS_SEGS),
      (const uint32_t*)(ws + WS_META), (uint32_t*)(ws + WS_META + 4096));
  k2c_scan<<<1, 1024, 0, stream>>>((const uint32_t*)(ws + WS_META + 4096),
      (uint32_t*)(ws + WS_META + 12288));
  k2d_scatter<<<128, 512, 0, stream>>>((const uint32_t*)(ws + WS_SEGS),
      (const uint32_t*)(ws + WS_META), (uint32_t*)(ws + WS_META + 12288),
      (uint32_t*)(ws + WS_SORTED));

  if (ws_size >= WS_NEED_SPLIT) {
    k3r_lstm<<<256, 1024, 0, stream>>>(x, done, h0, c0,
        (const short*)(ws + WS_WMAIN), (const float*)(ws + WS_BMAIN),
        (const uint32_t*)(ws + WS_SORTED), (const uint32_t*)(ws + WS_META),
        (short*)(ws + WS_HID), outHn, outCn);
    k4_heads<<<8192, 512, 0, stream>>>((const short*)(ws + WS_HID),
        (const short*)(ws + WS_WA1P), (const short*)(ws + WS_WV1P),
        (const short*)(ws + WS_WA2P), (const short*)(ws + WS_WV2P),
        ba1, bv1, ba2, bv2, wa3, ba3, wv3, bv3,
        mask, (const uint32_t*)(ws + WS_META + 16),
        outLogits, outValue);
  } else {
    k3_lstm_fused<<<256, 512, 0, stream>>>(x, done, h0, c0,
        (const short*)(ws + WS_WMAIN), (const float*)(ws + WS_BMAIN),
        (const short*)(ws + WS_WA1P), (const short*)(ws + WS_WV1P),
        (const short*)(ws + WS_WA2P), (const short*)(ws + WS_WV2P),
        ba1, bv1, ba2, bv2, wa3, ba3, wv3, bv3,
        mask, (const uint32_t*)(ws + WS_META + 16),
        (const uint32_t*)(ws + WS_SORTED), (const uint32_t*)(ws + WS_META),
        outLogits, outValue, outHn, outCn);
  }

  (void)in_sizes; (void)n_in; (void)out_size;
}